// Round 10
// baseline (304.627 us; speedup 1.0000x reference)
//
#include <hip/hip_runtime.h>
#include <hip/hip_bf16.h>
#include <math.h>

typedef unsigned short ushortT;
typedef __attribute__((ext_vector_type(8))) short short8;
typedef __attribute__((ext_vector_type(4))) float f32x4;

// Problem constants (fixed by the reference)
constexpr int NN   = 10000;    // nodes
constexpr int MP   = 10112;    // NN padded to multiple of 128 (79*128)
constexpr int EE   = 160000;   // edges (before self-loops)
constexpr int ETOT = EE + NN;  // edges incl. self-loops
constexpr int NG   = 64;       // graphs
constexpr int HID  = 256;
constexpr int HEADS = 4;

__device__ __forceinline__ ushortT f2bf(float x) {
    __hip_bfloat16 h = __float2bfloat16(x);
    return *reinterpret_cast<ushortT*>(&h);
}
__device__ __forceinline__ float bf2f(ushortT x) {
    unsigned u = ((unsigned)x) << 16;
    return __uint_as_float(u);
}

// bijective XCD-chunk swizzle (m204 variant; works for any nwg)
__device__ __forceinline__ int xcd_swz(int flat, int nwg) {
    int q = nwg >> 3, r = nwg & 7;
    int xcd = flat & 7, j = flat >> 3;
    return (xcd < r ? xcd * (q + 1) : r * (q + 1) + (xcd - r) * q) + j;
}

// ---------------------------------------------------------------------------
// SETUP mega-kernel: W2/W3 transpose-convert, block-diag W1, attention
// projections (wsv1/2/3), cnt zeroing.
// ---------------------------------------------------------------------------
__global__ __launch_bounds__(256) void setup_kernel(
        const float* __restrict__ W1, const float* __restrict__ as1,
        const float* __restrict__ ad1, float* __restrict__ wsv1,
        const float* __restrict__ W2, const float* __restrict__ as2,
        const float* __restrict__ ad2, float* __restrict__ wsv2,
        const float* __restrict__ W3, const float* __restrict__ as3,
        const float* __restrict__ ad3, float* __restrict__ wsv3,
        ushortT* __restrict__ wt2, ushortT* __restrict__ wt3,
        ushortT* __restrict__ b1p, int* __restrict__ cnt) {
    __shared__ float t[32][33];
    const int b = blockIdx.x, tid = threadIdx.x;
    if (b < 1280) {
        const float* W; ushortT* Wt; int N, n0, k0;
        if (b < 1024) { W = W2; Wt = wt2; N = 1024; n0 = (b & 31) * 32; k0 = (b >> 5) * 32; }
        else          { int b2 = b - 1024; W = W3; Wt = wt3; N = 256; n0 = (b2 & 7) * 32; k0 = (b2 >> 3) * 32; }
        const int K = 1024, Kp = 1024;
        int tx = tid & 31, ty = tid >> 5;
        for (int i = ty; i < 32; i += 8) {
            int k = k0 + i, n = n0 + tx;
            t[i][tx] = (k < K && n < N) ? W[(size_t)k * N + n] : 0.f;
        }
        __syncthreads();
        for (int i = ty; i < 32; i += 8) {
            int n = n0 + i, kp = k0 + tx;
            if (n < N && kp < Kp) Wt[(size_t)n * Kp + kp] = f2bf(t[tx][i]);
        }
    } else if (b < 1792) {
        int idx = (b - 1280) * 256 + tid;
        int n = idx >> 7, kp = idx & 127;
        int h = n >> 8, hk = kp >> 5, k = kp & 31;
        float v = (hk == h && k < 23) ? W1[(size_t)k * 1024 + n] : 0.f;
        b1p[idx] = f2bf(v);
    } else if (b < 4398) {
        int gw = (b - 1792) * 4 + (tid >> 6);
        int lane = tid & 63;
        const float *W, *atts, *attd; float* wsv; int heads, idx;
        if (gw < 184)            { W = W1; atts = as1; attd = ad1; wsv = wsv1; heads = 4; idx = gw; }
        else if (gw < 184 + 8192){ W = W2; atts = as2; attd = ad2; wsv = wsv2; heads = 4; idx = gw - 184; }
        else if (gw < 184 + 8192 + 2048) { W = W3; atts = as3; attd = ad3; wsv = wsv3; heads = 1; idx = gw - 184 - 8192; }
        else return;
        const int nout = 2 * heads;
        int k = idx / nout, o = idx - k * nout;
        int h = (o >= heads) ? (o - heads) : o;
        const float* att  = ((o >= heads) ? attd : atts) + h * HID;
        const float* wrow = W + (size_t)k * (heads * HID) + h * HID;
        float4 w4 = *(const float4*)(wrow + lane * 4);
        float4 a4 = *(const float4*)(att + lane * 4);
        float s = w4.x * a4.x + w4.y * a4.y + w4.z * a4.z + w4.w * a4.w;
        #pragma unroll
        for (int off = 1; off < 64; off <<= 1) s += __shfl_xor(s, off);
        if (lane == 0) wsv[(size_t)k * nout + o] = s;
    } else {
        int idx = (b - 4398) * 256 + tid;
        if (idx < NN) cnt[idx] = 0;
    }
}

// ---------------------------------------------------------------------------
// CSR build
// ---------------------------------------------------------------------------
__global__ void edge_count_kernel(const int* __restrict__ ei, int* __restrict__ cnt) {
    int e = blockIdx.x * blockDim.x + threadIdx.x;
    if (e >= ETOT) return;
    int dst = (e < EE) ? ei[EE + e] : (e - EE);
    atomicAdd(&cnt[dst], 1);
}

__global__ void scan_kernel(const int* __restrict__ cnt, int* __restrict__ row_ptr,
                            int* __restrict__ cursor) {
    __shared__ int part[256];
    int tid = threadIdx.x;
    const int chunk = (NN + 255) / 256;   // 40
    int s0 = tid * chunk;
    int s1 = min(NN, s0 + chunk);
    int sum = 0;
    for (int i = s0; i < s1; ++i) sum += cnt[i];
    part[tid] = sum;
    __syncthreads();
    for (int off = 1; off < 256; off <<= 1) {
        int v = (tid >= off) ? part[tid - off] : 0;
        __syncthreads();
        part[tid] += v;
        __syncthreads();
    }
    int run = (tid == 0) ? 0 : part[tid - 1];
    for (int i = s0; i < s1; ++i) {
        row_ptr[i] = run;
        cursor[i]  = run;
        run += cnt[i];
    }
    if (tid == 255) row_ptr[NN] = part[255];
}

// edge_fill + layer-1 dots (independent work) in one launch
__global__ void fill_dots1_kernel(const int* __restrict__ ei, int* __restrict__ cursor,
                                  int* __restrict__ col_src,
                                  const float* __restrict__ atom,
                                  const float* __restrict__ wsv1,
                                  float* __restrict__ a_s, float* __restrict__ a_d,
                                  int nfill) {
    int b = blockIdx.x;
    if (b < nfill) {
        int e = b * 256 + threadIdx.x;
        if (e >= ETOT) return;
        int src, dst;
        if (e < EE) { src = ei[e]; dst = ei[EE + e]; }
        else        { src = dst = e - EE; }
        int pos = atomicAdd(&cursor[dst], 1);
        col_src[pos] = src;
    } else {
        int n = (b - nfill) * 256 + threadIdx.x;
        if (n >= NN) return;
        float a[8] = {0.f, 0.f, 0.f, 0.f, 0.f, 0.f, 0.f, 0.f};
        #pragma unroll
        for (int k = 0; k < 23; ++k) {
            float x = atom[n * 23 + k];
            #pragma unroll
            for (int o = 0; o < 8; ++o) a[o] += x * wsv1[k * 8 + o];
        }
        #pragma unroll
        for (int h = 0; h < 4; ++h) { a_s[n * 4 + h] = a[h]; a_d[n * 4 + h] = a[4 + h]; }
    }
}

// ---------------------------------------------------------------------------
// layer-1 aggregate on RAW atom features
// ---------------------------------------------------------------------------
__global__ __launch_bounds__(256) void agg_atom_kernel(const float* __restrict__ atom,
                                                       const float* __restrict__ a_s,
                                                       const float* __restrict__ a_d,
                                                       const int* __restrict__ rowp,
                                                       const int* __restrict__ colv,
                                                       ushortT* __restrict__ Ap) {
    const int wv = threadIdx.x >> 6, lane = threadIdx.x & 63;
    const int i = blockIdx.x * 4 + wv;
    if (i >= NN) return;
    const int half = lane >> 5, c = lane & 31;
    const int start = rowp[i], end = rowp[i + 1];

    __shared__ float wsh[4][64][4];
    __shared__ int   ssh[4][64];

    float acc[4] = {0.f, 0.f, 0.f, 0.f};
    float den4[4] = {0.f, 0.f, 0.f, 0.f};
    for (int cb = start; cb < end; cb += 64) {
        int clen = min(64, end - cb);
        if (lane < clen) {
            int s = colv[cb + lane];
            ssh[wv][lane] = s;
            float4 as4 = *(const float4*)(a_s + (size_t)s * 4);
            float4 ad4 = *(const float4*)(a_d + (size_t)i * 4);
            float l0 = as4.x + ad4.x; l0 = (l0 >= 0.f) ? l0 : 0.2f * l0;
            float l1 = as4.y + ad4.y; l1 = (l1 >= 0.f) ? l1 : 0.2f * l1;
            float l2 = as4.z + ad4.z; l2 = (l2 >= 0.f) ? l2 : 0.2f * l2;
            float l3 = as4.w + ad4.w; l3 = (l3 >= 0.f) ? l3 : 0.2f * l3;
            float w0 = expf(l0), w1 = expf(l1), w2 = expf(l2), w3 = expf(l3);
            *reinterpret_cast<float4*>(&wsh[wv][lane][0]) = make_float4(w0, w1, w2, w3);
            den4[0] += w0; den4[1] += w1; den4[2] += w2; den4[3] += w3;
        }
        __builtin_amdgcn_wave_barrier();
        for (int e = half; e < clen; e += 2) {
            int s = ssh[wv][e];
            float x = (c < 23) ? atom[(size_t)s * 23 + c] : 0.f;
            acc[0] += wsh[wv][e][0] * x;
            acc[1] += wsh[wv][e][1] * x;
            acc[2] += wsh[wv][e][2] * x;
            acc[3] += wsh[wv][e][3] * x;
        }
        __builtin_amdgcn_wave_barrier();
    }
    #pragma unroll
    for (int h = 0; h < 4; ++h) acc[h] += __shfl_xor(acc[h], 32);
    #pragma unroll
    for (int off = 1; off < 64; off <<= 1) {
        den4[0] += __shfl_xor(den4[0], off);
        den4[1] += __shfl_xor(den4[1], off);
        den4[2] += __shfl_xor(den4[2], off);
        den4[3] += __shfl_xor(den4[3], off);
    }
    if (half == 0) {
        #pragma unroll
        for (int h = 0; h < 4; ++h) {
            float v = acc[h] / (den4[h] + 1e-16f);
            Ap[(size_t)i * 128 + h * 32 + c] = f2bf(v);
        }
    }
}

// ---------------------------------------------------------------------------
// Dedicated bf16 MFMA GEMM, M = MP (padded, multiple of 128): NO clamps, NO
// store guards — pad rows carry garbage that only lands in pad outputs.
// MODE 0: plain bf16 store. MODE 1: +bias,ELU.
// ---------------------------------------------------------------------------
__device__ __forceinline__ void gload_lds16(const ushortT* gsrc, ushortT* ldst) {
    __builtin_amdgcn_global_load_lds(
        (const __attribute__((address_space(1))) unsigned int*)gsrc,
        (__attribute__((address_space(3))) unsigned int*)ldst, 16, 0, 0);
}

template<int MODE>
__global__ __launch_bounds__(256, 2) void gemm_bf16(const ushortT* __restrict__ A,
                                                    const ushortT* __restrict__ Bt,
                                                    ushortT* __restrict__ C,
                                                    const float* __restrict__ bias,
                                                    int N, int K, int nx) {
    __shared__ ushortT lds[2][2][128][32];   // 32 KB
    const int tid  = threadIdx.x;
    const int lane = tid & 63, w = tid >> 6;
    const int wm = w >> 1, wn = w & 1;
    const int swz  = xcd_swz(blockIdx.x, gridDim.x);
    const int bx = swz % nx, by = swz / nx;
    const int row0 = by * 128;
    const int col0 = bx * 128;
    const int nt = K >> 5;

    auto stage = [&](int buf, int t) {
        int k0 = t << 5;
        #pragma unroll
        for (int i = 0; i < 2; ++i) {
            int gbase = (w * 2 + i) * 64;
            int g = gbase + lane;
            int row = g >> 2;
            int sw = (row & 3) ^ ((row >> 2) & 3);
            int koff = (g & 3) ^ sw;
            gload_lds16(A + (size_t)(row0 + row) * K + k0 + koff * 8,
                        &lds[buf][0][0][0] + gbase * 8);
            gload_lds16(Bt + (size_t)(col0 + row) * K + k0 + koff * 8,
                        &lds[buf][1][0][0] + gbase * 8);
        }
    };

    f32x4 acc[4][4] = {};
    const int lr = lane & 15, lk = lane >> 4;

    stage(0, 0);
    for (int t = 0; t < nt; ++t) {
        int buf = t & 1;
        __syncthreads();
        if (t + 1 < nt) stage(buf ^ 1, t + 1);
        short8 a[4], b[4];
        const ushortT* baseA = &lds[buf][0][0][0];
        const ushortT* baseB = &lds[buf][1][0][0];
        #pragma unroll
        for (int m = 0; m < 4; ++m) {
            int row = wm * 64 + m * 16 + lr;
            int sw = (row & 3) ^ ((row >> 2) & 3);
            a[m] = *(const short8*)(baseA + row * 32 + ((lk ^ sw) * 8));
        }
        #pragma unroll
        for (int n = 0; n < 4; ++n) {
            int row = wn * 64 + n * 16 + lr;
            int sw = (row & 3) ^ ((row >> 2) & 3);
            b[n] = *(const short8*)(baseB + row * 32 + ((lk ^ sw) * 8));
        }
        #pragma unroll
        for (int m = 0; m < 4; ++m)
            #pragma unroll
            for (int n = 0; n < 4; ++n)
                acc[m][n] = __builtin_amdgcn_mfma_f32_16x16x32_bf16(a[m], b[n], acc[m][n], 0, 0, 0);
    }

    // epilogue: C/D layout col=lane&15, row=(lane>>4)*4+reg
    #pragma unroll
    for (int m = 0; m < 4; ++m) {
        #pragma unroll
        for (int n = 0; n < 4; ++n) {
            int col = col0 + wn * 64 + n * 16 + lr;
            float bv = (MODE == 1) ? bias[col] : 0.f;
            #pragma unroll
            for (int j = 0; j < 4; ++j) {
                int rowg = row0 + wm * 64 + m * 16 + lk * 4 + j;
                float v = acc[m][n][j];
                if (MODE == 1) { v += bv; v = (v > 0.f) ? v : expm1f(v); }
                C[(size_t)rowg * N + col] = f2bf(v);
            }
        }
    }
}

// layer-2 dots: a[n,o] = sum_c x2[n,c] * wsv2[c,o]. One wave per node.
__global__ void dots2_kernel(const ushortT* __restrict__ x,
                             const float* __restrict__ wsv,
                             float* __restrict__ a_s, float* __restrict__ a_d) {
    int gw = (blockIdx.x * 256 + threadIdx.x) >> 6;
    int lane = threadIdx.x & 63;
    if (gw >= NN) return;
    const ushortT* row = x + (size_t)gw * 1024 + lane * 16;
    short8 v0 = *(const short8*)row;
    short8 v1 = *(const short8*)(row + 8);
    float ps[8] = {0.f, 0.f, 0.f, 0.f, 0.f, 0.f, 0.f, 0.f};
    const float* wb = wsv + (size_t)lane * 16 * 8;
    #pragma unroll
    for (int c = 0; c < 8; ++c) {
        float xv = bf2f((ushortT)v0[c]);
        #pragma unroll
        for (int o = 0; o < 8; ++o) ps[o] += xv * wb[c * 8 + o];
    }
    #pragma unroll
    for (int c = 0; c < 8; ++c) {
        float xv = bf2f((ushortT)v1[c]);
        #pragma unroll
        for (int o = 0; o < 8; ++o) ps[o] += xv * wb[(8 + c) * 8 + o];
    }
    #pragma unroll
    for (int off = 1; off < 64; off <<= 1) {
        #pragma unroll
        for (int o = 0; o < 8; ++o) ps[o] += __shfl_xor(ps[o], off);
    }
    if (lane == 0) {
        #pragma unroll
        for (int h = 0; h < 4; ++h) { a_s[gw * 4 + h] = ps[h]; a_d[gw * 4 + h] = ps[4 + h]; }
    }
}

// layer-3 dots (heads=1): two outputs per node.
__global__ void dots3_kernel(const ushortT* __restrict__ x,
                             const float* __restrict__ wsv,
                             float* __restrict__ a_s, float* __restrict__ a_d) {
    int gw = (blockIdx.x * 256 + threadIdx.x) >> 6;
    int lane = threadIdx.x & 63;
    if (gw >= NN) return;
    const ushortT* row = x + (size_t)gw * 1024 + lane * 16;
    short8 v0 = *(const short8*)row;
    short8 v1 = *(const short8*)(row + 8);
    float p0 = 0.f, p1 = 0.f;
    const int c0 = lane * 16;
    #pragma unroll
    for (int c = 0; c < 8; ++c) {
        float xv = bf2f((ushortT)v0[c]);
        float2 w2 = *(const float2*)(wsv + (size_t)(c0 + c) * 2);
        p0 += xv * w2.x; p1 += xv * w2.y;
    }
    #pragma unroll
    for (int c = 0; c < 8; ++c) {
        float xv = bf2f((ushortT)v1[c]);
        float2 w2 = *(const float2*)(wsv + (size_t)(c0 + 8 + c) * 2);
        p0 += xv * w2.x; p1 += xv * w2.y;
    }
    #pragma unroll
    for (int off = 1; off < 64; off <<= 1) {
        p0 += __shfl_xor(p0, off);
        p1 += __shfl_xor(p1, off);
    }
    if (lane == 0) { a_s[gw] = p0; a_d[gw] = p1; }
}

// ---------------------------------------------------------------------------
// GAT aggregation heads=4 (C=1024): one WAVE per node, lane owns 16 ch.
// Measured floor ~60us (random edges; each XCD pulls ~whole h through L2).
// ---------------------------------------------------------------------------
__global__ __launch_bounds__(256) void gat_agg_h4(const ushortT* __restrict__ hfeat,
                                                  const float* __restrict__ a_s,
                                                  const float* __restrict__ a_d,
                                                  const int* __restrict__ rowp,
                                                  const int* __restrict__ colv,
                                                  const float* __restrict__ bias,
                                                  ushortT* __restrict__ out16) {
    const int wv = threadIdx.x >> 6, lane = threadIdx.x & 63;
    const int i = blockIdx.x * 4 + wv;
    if (i >= NN) return;
    const int c0 = lane * 16;
    const int hh = c0 >> 8;
    const int start = rowp[i], end = rowp[i + 1];

    __shared__ float wsh[4][64][4];
    __shared__ int   ssh[4][64];

    float acc[16];
    #pragma unroll
    for (int c = 0; c < 16; ++c) acc[c] = 0.f;
    float den4[4] = {0.f, 0.f, 0.f, 0.f};

    for (int cb = start; cb < end; cb += 64) {
        int clen = min(64, end - cb);
        if (lane < clen) {
            int s = colv[cb + lane];
            ssh[wv][lane] = s;
            float4 as4 = *(const float4*)(a_s + (size_t)s * 4);
            float4 ad4 = *(const float4*)(a_d + (size_t)i * 4);
            float l0 = as4.x + ad4.x; l0 = (l0 >= 0.f) ? l0 : 0.2f * l0;
            float l1 = as4.y + ad4.y; l1 = (l1 >= 0.f) ? l1 : 0.2f * l1;
            float l2 = as4.z + ad4.z; l2 = (l2 >= 0.f) ? l2 : 0.2f * l2;
            float l3 = as4.w + ad4.w; l3 = (l3 >= 0.f) ? l3 : 0.2f * l3;
            float w0 = expf(l0), w1 = expf(l1), w2 = expf(l2), w3 = expf(l3);
            *reinterpret_cast<float4*>(&wsh[wv][lane][0]) = make_float4(w0, w1, w2, w3);
            den4[0] += w0; den4[1] += w1; den4[2] += w2; den4[3] += w3;
        }
        __builtin_amdgcn_wave_barrier();
        int e = 0;
        for (; e + 4 <= clen; e += 4) {
            int sa = ssh[wv][e], sb = ssh[wv][e + 1], sc = ssh[wv][e + 2], sd = ssh[wv][e + 3];
            const ushortT* pa = hfeat + (size_t)sa * 1024 + c0;
            const ushortT* pb = hfeat + (size_t)sb * 1024 + c0;
            const ushortT* pc = hfeat + (size_t)sc * 1024 + c0;
            const ushortT* pd = hfeat + (size_t)sd * 1024 + c0;
            short8 va0 = *(const short8*)pa,       va1 = *(const short8*)(pa + 8);
            short8 vb0 = *(const short8*)pb,       vb1 = *(const short8*)(pb + 8);
            short8 vc0 = *(const short8*)pc,       vc1 = *(const short8*)(pc + 8);
            short8 vd0 = *(const short8*)pd,       vd1 = *(const short8*)(pd + 8);
            float wa = wsh[wv][e][hh],     wb = wsh[wv][e + 1][hh];
            float wc = wsh[wv][e + 2][hh], wd = wsh[wv][e + 3][hh];
            #pragma unroll
            for (int j = 0; j < 8; ++j) {
                acc[j]     += wa * bf2f((ushortT)va0[j]) + wb * bf2f((ushortT)vb0[j])
                            + wc * bf2f((ushortT)vc0[j]) + wd * bf2f((ushortT)vd0[j]);
                acc[8 + j] += wa * bf2f((ushortT)va1[j]) + wb * bf2f((ushortT)vb1[j])
                            + wc * bf2f((ushortT)vc1[j]) + wd * bf2f((ushortT)vd1[j]);
            }
        }
        for (; e < clen; ++e) {
            int s = ssh[wv][e];
            float wgt = wsh[wv][e][hh];
            const ushortT* p = hfeat + (size_t)s * 1024 + c0;
            short8 v0 = *(const short8*)p;
            short8 v1 = *(const short8*)(p + 8);
            #pragma unroll
            for (int j = 0; j < 8; ++j) {
                acc[j]     += wgt * bf2f((ushortT)v0[j]);
                acc[8 + j] += wgt * bf2f((ushortT)v1[j]);
            }
        }
        __builtin_amdgcn_wave_barrier();
    }

    #pragma unroll
    for (int off = 1; off < 64; off <<= 1) {
        den4[0] += __shfl_xor(den4[0], off);
        den4[1] += __shfl_xor(den4[1], off);
        den4[2] += __shfl_xor(den4[2], off);
        den4[3] += __shfl_xor(den4[3], off);
    }
    float den = (hh == 0) ? den4[0] : (hh == 1) ? den4[1] : (hh == 2) ? den4[2] : den4[3];
    float inv = 1.f / (den + 1e-16f);

    ushortT pk[16];
    #pragma unroll
    for (int c = 0; c < 16; ++c) {
        float v = acc[c] * inv + bias[c0 + c];
        v = (v > 0.f) ? v : expm1f(v);           // ELU
        pk[c] = f2bf(v);
    }
    *reinterpret_cast<short8*>(out16 + (size_t)i * 1024 + c0)     = *reinterpret_cast<short8*>(&pk[0]);
    *reinterpret_cast<short8*>(out16 + (size_t)i * 1024 + c0 + 8) = *reinterpret_cast<short8*>(&pk[8]);
}

// heads=1 (C=256): one wave per node, 4 channels/lane, fp32 out + bias + ELU.
__global__ __launch_bounds__(256) void gat_agg_h1(const ushortT* __restrict__ hfeat,
                                                  const float* __restrict__ a_s,
                                                  const float* __restrict__ a_d,
                                                  const int* __restrict__ rowp,
                                                  const int* __restrict__ colv,
                                                  const float* __restrict__ bias,
                                                  float* __restrict__ outf) {
    const int wv = threadIdx.x >> 6, lane = threadIdx.x & 63;
    const int i = blockIdx.x * 4 + wv;
    if (i >= NN) return;
    const int c0 = lane * 4;
    const int start = rowp[i], end = rowp[i + 1];
    const float adi = a_d[i];

    __shared__ float wsh[4][64];
    __shared__ int   ssh[4][64];

    float acc[4] = {0.f, 0.f, 0.f, 0.f};
    float den = 0.f;

    for (int cb = start; cb < end; cb += 64) {
        int clen = min(64, end - cb);
        if (lane < clen) {
            int s = colv[cb + lane];
            ssh[wv][lane] = s;
            float l = a_s[s] + adi;
            l = (l >= 0.f) ? l : 0.2f * l;
            float w0 = expf(l);
            wsh[wv][lane] = w0;
            den += w0;
        }
        __builtin_amdgcn_wave_barrier();
        int e = 0;
        for (; e + 4 <= clen; e += 4) {
            int sa = ssh[wv][e], sb = ssh[wv][e + 1], sc = ssh[wv][e + 2], sd = ssh[wv][e + 3];
            ushort4 va = *(const ushort4*)(hfeat + (size_t)sa * 256 + c0);
            ushort4 vb = *(const ushort4*)(hfeat + (size_t)sb * 256 + c0);
            ushort4 vc = *(const ushort4*)(hfeat + (size_t)sc * 256 + c0);
            ushort4 vd = *(const ushort4*)(hfeat + (size_t)sd * 256 + c0);
            float wa = wsh[wv][e], wb2 = wsh[wv][e + 1], wc2 = wsh[wv][e + 2], wd2 = wsh[wv][e + 3];
            acc[0] += wa * bf2f(va.x) + wb2 * bf2f(vb.x) + wc2 * bf2f(vc.x) + wd2 * bf2f(vd.x);
            acc[1] += wa * bf2f(va.y) + wb2 * bf2f(vb.y) + wc2 * bf2f(vc.y) + wd2 * bf2f(vd.y);
            acc[2] += wa * bf2f(va.z) + wb2 * bf2f(vb.z) + wc2 * bf2f(vc.z) + wd2 * bf2f(vd.z);
            acc[3] += wa * bf2f(va.w) + wb2 * bf2f(vb.w) + wc2 * bf2f(vc.w) + wd2 * bf2f(vd.w);
        }
        for (; e < clen; ++e) {
            int s = ssh[wv][e];
            float wgt = wsh[wv][e];
            ushort4 v = *(const ushort4*)(hfeat + (size_t)s * 256 + c0);
            acc[0] += wgt * bf2f(v.x); acc[1] += wgt * bf2f(v.y);
            acc[2] += wgt * bf2f(v.z); acc[3] += wgt * bf2f(v.w);
        }
        __builtin_amdgcn_wave_barrier();
    }

    #pragma unroll
    for (int off = 1; off < 64; off <<= 1) den += __shfl_xor(den, off);
    float inv = 1.f / (den + 1e-16f);

    float4 o4;
    float v0 = acc[0] * inv + bias[c0 + 0]; o4.x = (v0 > 0.f) ? v0 : expm1f(v0);
    float v1 = acc[1] * inv + bias[c0 + 1]; o4.y = (v1 > 0.f) ? v1 : expm1f(v1);
    float v2 = acc[2] * inv + bias[c0 + 2]; o4.z = (v2 > 0.f) ? v2 : expm1f(v2);
    float v3 = acc[3] * inv + bias[c0 + 3]; o4.w = (v3 > 0.f) ? v3 : expm1f(v3);
    *reinterpret_cast<float4*>(outf + (size_t)i * 256 + c0) = o4;
}

// ---------------------------------------------------------------------------
// global mean pool + MLP head
// ---------------------------------------------------------------------------
__global__ void pool_mlp(const float* __restrict__ x,
                         const int* __restrict__ batch,
                         const float* __restrict__ fc1_w,
                         const float* __restrict__ fc1_b,
                         const float* __restrict__ fc2_w,
                         const float* __restrict__ fc2_b,
                         float* __restrict__ out) {
    int g = blockIdx.x, tid = threadIdx.x;
    int lo = 0, hi = NN;
    while (lo < hi) { int mid = (lo + hi) >> 1; if (batch[mid] < g) lo = mid + 1; else hi = mid; }
    int s0 = lo;
    lo = 0; hi = NN;
    while (lo < hi) { int mid = (lo + hi) >> 1; if (batch[mid] < g + 1) lo = mid + 1; else hi = mid; }
    int s1 = lo;

    float acc = 0.f;
    for (int n = s0; n < s1; ++n) acc += x[(size_t)n * HID + tid];
    float cnt = (float)(s1 - s0);
    float feat = acc / fmaxf(cnt, 1.f);
    out[NG + g * HID + tid] = feat;

    __shared__ float fsh[HID];
    fsh[tid] = feat;
    __syncthreads();
    __shared__ float r2[128];
    if (tid < 128) {
        float a = fc1_b[tid];
        for (int c = 0; c < HID; ++c) a += fsh[c] * fc1_w[c * 128 + tid];
        a = fmaxf(a, 0.f);
        r2[tid] = a * fc2_w[tid];
    }
    __syncthreads();
    for (int s2 = 64; s2 > 0; s2 >>= 1) {
        if (tid < s2) r2[tid] += r2[tid + s2];
        __syncthreads();
    }
    if (tid == 0) out[g] = r2[0] + fc2_b[0];
}

// ---------------------------------------------------------------------------
extern "C" void kernel_launch(void* const* d_in, const int* in_sizes, int n_in,
                              void* d_out, int out_size, void* d_ws, size_t ws_size,
                              hipStream_t stream) {
    const float* atom  = (const float*)d_in[0];
    const int*   ei    = (const int*)  d_in[1];
    const int*   batch = (const int*)  d_in[2];
    const float* W1  = (const float*)d_in[3];
    const float* as1 = (const float*)d_in[4];
    const float* ad1 = (const float*)d_in[5];
    const float* b1  = (const float*)d_in[6];
    const float* W2  = (const float*)d_in[7];
    const float* as2 = (const float*)d_in[8];
    const float* ad2 = (const float*)d_in[9];
    const float* b2  = (const float*)d_in[10];
    const float* W3  = (const float*)d_in[11];
    const float* as3 = (const float*)d_in[12];
    const float* ad3 = (const float*)d_in[13];
    const float* b3  = (const float*)d_in[14];
    const float* fc1w = (const float*)d_in[15];
    const float* fc1b = (const float*)d_in[16];
    const float* fc2w = (const float*)d_in[17];
    const float* fc2b = (const float*)d_in[18];
    float* out = (float*)d_out;

    // workspace layout (16B-aligned sections; M-padded matrices)
    ushortT* h16  = (ushortT*)d_ws;                       // [MP,1024] bf16
    ushortT* x16  = h16 + (size_t)MP * 1024;              // [MP,1024] bf16
    ushortT* Ap   = x16 + (size_t)MP * 1024;              // [MP,128]  bf16
    ushortT* b1p  = Ap + (size_t)MP * 128;                // [1024,128] bf16
    ushortT* wt2  = b1p + 1024 * 128;                     // [1024,1024] bf16
    ushortT* wt3  = wt2 + 1024 * 1024;                    // [256,1024] bf16
    float*   x3   = (float*)(wt3 + 256 * 1024);           // [NN,256] f32
    float*   asL1 = x3 + (size_t)NN * 256;                // [NN,4]
    float*   adL1 = asL1 + (size_t)NN * 4;                // [NN,4]
    float*   asL2 = adL1 + (size_t)NN * 4;                // [NN,4]
    float*   adL2 = asL2 + (size_t)NN * 4;                // [NN,4]
    float*   asL3 = adL2 + (size_t)NN * 4;                // [NN]
    float*   adL3 = asL3 + NN;                            // [NN]
    float*   wsv1 = adL3 + NN;                            // [23,8]
    float*   wsv2 = wsv1 + 23 * 8;                        // [1024,8]
    float*   wsv3 = wsv2 + 1024 * 8;                      // [1024,2]
    int*   cnt    = (int*)(wsv3 + 1024 * 2);              // [NN]
    int*   rowp   = cnt + NN;                             // [NN+1]
    int*   cursor = rowp + NN + 1;                        // [NN]
    int*   col    = cursor + NN;                          // [ETOT]

    dim3 blk(256);
    const int gagg = (NN + 3) / 4;           // 2500
    const int gy   = MP / 128;               // 79

    // ---- setup (1 launch) ----
    setup_kernel<<<4438, blk, 0, stream>>>(W1, as1, ad1, wsv1, W2, as2, ad2, wsv2,
                                           W3, as3, ad3, wsv3, wt2, wt3, b1p, cnt);

    // ---- CSR build + layer-1 dots ----
    edge_count_kernel<<<(ETOT + 255) / 256, blk, 0, stream>>>(ei, cnt);
    scan_kernel<<<1, blk, 0, stream>>>(cnt, rowp, cursor);
    const int nfill = (ETOT + 255) / 256;    // 665
    fill_dots1_kernel<<<nfill + (NN + 255) / 256, blk, 0, stream>>>(
        ei, cursor, col, atom, wsv1, asL1, adL1, nfill);

    // ---- layer 1 ----
    agg_atom_kernel<<<gagg, blk, 0, stream>>>(atom, asL1, adL1, rowp, col, Ap);
    gemm_bf16<1><<<8 * gy, blk, 0, stream>>>(Ap, b1p, x16, b1, 1024, 128, 8);

    // ---- layer 2 ----
    dots2_kernel<<<gagg, blk, 0, stream>>>(x16, wsv2, asL2, adL2);
    gemm_bf16<0><<<8 * gy, blk, 0, stream>>>(x16, wt2, h16, nullptr, 1024, 1024, 8);
    gat_agg_h4<<<gagg, blk, 0, stream>>>(h16, asL2, adL2, rowp, col, b2, x16);

    // ---- layer 3 ----
    dots3_kernel<<<gagg, blk, 0, stream>>>(x16, wsv3, asL3, adL3);
    gemm_bf16<0><<<2 * gy, blk, 0, stream>>>(x16, wt3, h16, nullptr, 256, 1024, 2);
    gat_agg_h1<<<gagg, blk, 0, stream>>>(h16, asL3, adL3, rowp, col, b3, x3);

    // ---- pool + MLP head ----
    pool_mlp<<<NG, blk, 0, stream>>>(x3, batch, fc1w, fc1b, fc2w, fc2b, out);
}

// Round 11
// 293.623 us; speedup vs baseline: 1.0375x; 1.0375x over previous
//
#include <hip/hip_runtime.h>
#include <hip/hip_bf16.h>
#include <math.h>

typedef unsigned short ushortT;
typedef __attribute__((ext_vector_type(8))) short short8;
typedef __attribute__((ext_vector_type(4))) float f32x4;

// Problem constants (fixed by the reference)
constexpr int NN   = 10000;    // nodes
constexpr int MP   = 10112;    // NN padded to multiple of 128 (79*128)
constexpr int EE   = 160000;   // edges (before self-loops)
constexpr int ETOT = EE + NN;  // edges incl. self-loops
constexpr int NG   = 64;       // graphs
constexpr int HID  = 256;
constexpr int HEADS = 4;

__device__ __forceinline__ ushortT f2bf(float x) {
    __hip_bfloat16 h = __float2bfloat16(x);
    return *reinterpret_cast<ushortT*>(&h);
}
__device__ __forceinline__ float bf2f(ushortT x) {
    unsigned u = ((unsigned)x) << 16;
    return __uint_as_float(u);
}

// bijective XCD-chunk swizzle (m204 variant; works for any nwg)
__device__ __forceinline__ int xcd_swz(int flat, int nwg) {
    int q = nwg >> 3, r = nwg & 7;
    int xcd = flat & 7, j = flat >> 3;
    return (xcd < r ? xcd * (q + 1) : r * (q + 1) + (xcd - r) * q) + j;
}

// ---------------------------------------------------------------------------
// SETUP mega-kernel: W2/W3 transpose-convert, block-diag W1, attention
// projections (wsv1/2/3), and the CSR edge histogram (cnt pre-zeroed by
// memset). Block ranges: [0,1280) wt tiles; [1280,1792) b1p; [1792,4398)
// proj waves; [4398,5063) edge count.
// ---------------------------------------------------------------------------
__global__ __launch_bounds__(256) void setup_kernel(
        const float* __restrict__ W1, const float* __restrict__ as1,
        const float* __restrict__ ad1, float* __restrict__ wsv1,
        const float* __restrict__ W2, const float* __restrict__ as2,
        const float* __restrict__ ad2, float* __restrict__ wsv2,
        const float* __restrict__ W3, const float* __restrict__ as3,
        const float* __restrict__ ad3, float* __restrict__ wsv3,
        ushortT* __restrict__ wt2, ushortT* __restrict__ wt3,
        ushortT* __restrict__ b1p, const int* __restrict__ ei,
        int* __restrict__ cnt) {
    __shared__ float t[32][33];
    const int b = blockIdx.x, tid = threadIdx.x;
    if (b < 1280) {
        const float* W; ushortT* Wt; int N, n0, k0;
        if (b < 1024) { W = W2; Wt = wt2; N = 1024; n0 = (b & 31) * 32; k0 = (b >> 5) * 32; }
        else          { int b2 = b - 1024; W = W3; Wt = wt3; N = 256; n0 = (b2 & 7) * 32; k0 = (b2 >> 3) * 32; }
        const int K = 1024, Kp = 1024;
        int tx = tid & 31, ty = tid >> 5;
        for (int i = ty; i < 32; i += 8) {
            int k = k0 + i, n = n0 + tx;
            t[i][tx] = (k < K && n < N) ? W[(size_t)k * N + n] : 0.f;
        }
        __syncthreads();
        for (int i = ty; i < 32; i += 8) {
            int n = n0 + i, kp = k0 + tx;
            if (n < N && kp < Kp) Wt[(size_t)n * Kp + kp] = f2bf(t[tx][i]);
        }
    } else if (b < 1792) {
        int idx = (b - 1280) * 256 + tid;
        int n = idx >> 7, kp = idx & 127;
        int h = n >> 8, hk = kp >> 5, k = kp & 31;
        float v = (hk == h && k < 23) ? W1[(size_t)k * 1024 + n] : 0.f;
        b1p[idx] = f2bf(v);
    } else if (b < 4398) {
        int gw = (b - 1792) * 4 + (tid >> 6);
        int lane = tid & 63;
        const float *W, *atts, *attd; float* wsv; int heads, idx;
        if (gw < 184)            { W = W1; atts = as1; attd = ad1; wsv = wsv1; heads = 4; idx = gw; }
        else if (gw < 184 + 8192){ W = W2; atts = as2; attd = ad2; wsv = wsv2; heads = 4; idx = gw - 184; }
        else if (gw < 184 + 8192 + 2048) { W = W3; atts = as3; attd = ad3; wsv = wsv3; heads = 1; idx = gw - 184 - 8192; }
        else return;
        const int nout = 2 * heads;
        int k = idx / nout, o = idx - k * nout;
        int h = (o >= heads) ? (o - heads) : o;
        const float* att  = ((o >= heads) ? attd : atts) + h * HID;
        const float* wrow = W + (size_t)k * (heads * HID) + h * HID;
        float4 w4 = *(const float4*)(wrow + lane * 4);
        float4 a4 = *(const float4*)(att + lane * 4);
        float s = w4.x * a4.x + w4.y * a4.y + w4.z * a4.z + w4.w * a4.w;
        #pragma unroll
        for (int off = 1; off < 64; off <<= 1) s += __shfl_xor(s, off);
        if (lane == 0) wsv[(size_t)k * nout + o] = s;
    } else {
        int e = (b - 4398) * 256 + tid;
        if (e >= ETOT) return;
        int dst = (e < EE) ? ei[EE + e] : (e - EE);
        atomicAdd(&cnt[dst], 1);
    }
}

__global__ void scan_kernel(const int* __restrict__ cnt, int* __restrict__ row_ptr,
                            int* __restrict__ cursor) {
    __shared__ int part[256];
    int tid = threadIdx.x;
    const int chunk = (NN + 255) / 256;   // 40
    int s0 = tid * chunk;
    int s1 = min(NN, s0 + chunk);
    int sum = 0;
    for (int i = s0; i < s1; ++i) sum += cnt[i];
    part[tid] = sum;
    __syncthreads();
    for (int off = 1; off < 256; off <<= 1) {
        int v = (tid >= off) ? part[tid - off] : 0;
        __syncthreads();
        part[tid] += v;
        __syncthreads();
    }
    int run = (tid == 0) ? 0 : part[tid - 1];
    for (int i = s0; i < s1; ++i) {
        row_ptr[i] = run;
        cursor[i]  = run;
        run += cnt[i];
    }
    if (tid == 255) row_ptr[NN] = part[255];
}

// edge_fill + layer-1 dots (independent work) in one launch
__global__ void fill_dots1_kernel(const int* __restrict__ ei, int* __restrict__ cursor,
                                  int* __restrict__ col_src,
                                  const float* __restrict__ atom,
                                  const float* __restrict__ wsv1,
                                  float* __restrict__ a_s, float* __restrict__ a_d,
                                  int nfill) {
    int b = blockIdx.x;
    if (b < nfill) {
        int e = b * 256 + threadIdx.x;
        if (e >= ETOT) return;
        int src, dst;
        if (e < EE) { src = ei[e]; dst = ei[EE + e]; }
        else        { src = dst = e - EE; }
        int pos = atomicAdd(&cursor[dst], 1);
        col_src[pos] = src;
    } else {
        int n = (b - nfill) * 256 + threadIdx.x;
        if (n >= NN) return;
        float a[8] = {0.f, 0.f, 0.f, 0.f, 0.f, 0.f, 0.f, 0.f};
        #pragma unroll
        for (int k = 0; k < 23; ++k) {
            float x = atom[n * 23 + k];
            #pragma unroll
            for (int o = 0; o < 8; ++o) a[o] += x * wsv1[k * 8 + o];
        }
        #pragma unroll
        for (int h = 0; h < 4; ++h) { a_s[n * 4 + h] = a[h]; a_d[n * 4 + h] = a[4 + h]; }
    }
}

// ---------------------------------------------------------------------------
// layer-1 aggregate on RAW atom features
// ---------------------------------------------------------------------------
__global__ __launch_bounds__(256) void agg_atom_kernel(const float* __restrict__ atom,
                                                       const float* __restrict__ a_s,
                                                       const float* __restrict__ a_d,
                                                       const int* __restrict__ rowp,
                                                       const int* __restrict__ colv,
                                                       ushortT* __restrict__ Ap) {
    const int wv = threadIdx.x >> 6, lane = threadIdx.x & 63;
    const int i = blockIdx.x * 4 + wv;
    if (i >= NN) return;
    const int half = lane >> 5, c = lane & 31;
    const int start = rowp[i], end = rowp[i + 1];

    __shared__ float wsh[4][64][4];
    __shared__ int   ssh[4][64];

    float acc[4] = {0.f, 0.f, 0.f, 0.f};
    float den4[4] = {0.f, 0.f, 0.f, 0.f};
    for (int cb = start; cb < end; cb += 64) {
        int clen = min(64, end - cb);
        if (lane < clen) {
            int s = colv[cb + lane];
            ssh[wv][lane] = s;
            float4 as4 = *(const float4*)(a_s + (size_t)s * 4);
            float4 ad4 = *(const float4*)(a_d + (size_t)i * 4);
            float l0 = as4.x + ad4.x; l0 = (l0 >= 0.f) ? l0 : 0.2f * l0;
            float l1 = as4.y + ad4.y; l1 = (l1 >= 0.f) ? l1 : 0.2f * l1;
            float l2 = as4.z + ad4.z; l2 = (l2 >= 0.f) ? l2 : 0.2f * l2;
            float l3 = as4.w + ad4.w; l3 = (l3 >= 0.f) ? l3 : 0.2f * l3;
            float w0 = expf(l0), w1 = expf(l1), w2 = expf(l2), w3 = expf(l3);
            *reinterpret_cast<float4*>(&wsh[wv][lane][0]) = make_float4(w0, w1, w2, w3);
            den4[0] += w0; den4[1] += w1; den4[2] += w2; den4[3] += w3;
        }
        __builtin_amdgcn_wave_barrier();
        for (int e = half; e < clen; e += 2) {
            int s = ssh[wv][e];
            float x = (c < 23) ? atom[(size_t)s * 23 + c] : 0.f;
            acc[0] += wsh[wv][e][0] * x;
            acc[1] += wsh[wv][e][1] * x;
            acc[2] += wsh[wv][e][2] * x;
            acc[3] += wsh[wv][e][3] * x;
        }
        __builtin_amdgcn_wave_barrier();
    }
    #pragma unroll
    for (int h = 0; h < 4; ++h) acc[h] += __shfl_xor(acc[h], 32);
    #pragma unroll
    for (int off = 1; off < 64; off <<= 1) {
        den4[0] += __shfl_xor(den4[0], off);
        den4[1] += __shfl_xor(den4[1], off);
        den4[2] += __shfl_xor(den4[2], off);
        den4[3] += __shfl_xor(den4[3], off);
    }
    if (half == 0) {
        #pragma unroll
        for (int h = 0; h < 4; ++h) {
            float v = acc[h] / (den4[h] + 1e-16f);
            Ap[(size_t)i * 128 + h * 32 + c] = f2bf(v);
        }
    }
}

// ---------------------------------------------------------------------------
// bf16 MFMA GEMM, M = MP (padded): templated K-step (32 or 64). KS=64 halves
// the barrier/drain count for K=1024. Optional extra blocks run the
// next-layer dot kernels (read-only shared input A — legal in one launch).
// MODE 0: plain bf16 store. MODE 1: +bias,ELU.
// ---------------------------------------------------------------------------
__device__ __forceinline__ void gload_lds16(const ushortT* gsrc, ushortT* ldst) {
    __builtin_amdgcn_global_load_lds(
        (const __attribute__((address_space(1))) unsigned int*)gsrc,
        (__attribute__((address_space(3))) unsigned int*)ldst, 16, 0, 0);
}

template<int MODE, int KS, int DOTS>
__global__ __launch_bounds__(256, 2) void gemm_bf16(const ushortT* __restrict__ A,
                                                    const ushortT* __restrict__ Bt,
                                                    ushortT* __restrict__ C,
                                                    const float* __restrict__ bias,
                                                    const float* __restrict__ wsv,
                                                    float* __restrict__ da_s,
                                                    float* __restrict__ da_d,
                                                    int N, int K, int nx, int ngemm) {
    __shared__ ushortT lds[2][2][128][KS];
    if ((int)blockIdx.x < ngemm) {
        const int tid  = threadIdx.x;
        const int lane = tid & 63, w = tid >> 6;
        const int wm = w >> 1, wn = w & 1;
        const int swz  = xcd_swz(blockIdx.x, ngemm);
        const int bx = swz % nx, by = swz / nx;
        const int row0 = by * 128;
        const int col0 = bx * 128;
        const int nt = K / KS;
        constexpr int GPR = KS / 8;            // granules per row (4 or 8)
        constexpr int PT  = 128 * GPR / 256;   // granules per thread (2 or 4)

        auto stage = [&](int buf, int t) {
            int k0 = t * KS;
            #pragma unroll
            for (int i = 0; i < PT; ++i) {
                int g = i * 256 + tid;            // wave-contiguous LDS dest
                int row = g / GPR, gi = g % GPR;
                int sw = (KS == 64) ? (row & 7) : ((row & 3) ^ ((row >> 2) & 3));
                int koff = gi ^ sw;
                gload_lds16(A + (size_t)(row0 + row) * K + k0 + koff * 8,
                            &lds[buf][0][0][0] + g * 8);
                gload_lds16(Bt + (size_t)(col0 + row) * K + k0 + koff * 8,
                            &lds[buf][1][0][0] + g * 8);
            }
        };

        f32x4 acc[4][4] = {};
        const int lr = lane & 15, lk = lane >> 4;

        stage(0, 0);
        for (int t = 0; t < nt; ++t) {
            int buf = t & 1;
            __syncthreads();
            if (t + 1 < nt) stage(buf ^ 1, t + 1);
            const ushortT* baseA = &lds[buf][0][0][0];
            const ushortT* baseB = &lds[buf][1][0][0];
            #pragma unroll
            for (int kk = 0; kk < KS / 32; ++kk) {
                short8 a[4], b[4];
                #pragma unroll
                for (int m = 0; m < 4; ++m) {
                    int row = wm * 64 + m * 16 + lr;
                    int sw = (KS == 64) ? (row & 7) : ((row & 3) ^ ((row >> 2) & 3));
                    int gidx = (kk * 4 + lk) ^ sw;
                    a[m] = *(const short8*)(baseA + row * KS + gidx * 8);
                }
                #pragma unroll
                for (int n = 0; n < 4; ++n) {
                    int row = wn * 64 + n * 16 + lr;
                    int sw = (KS == 64) ? (row & 7) : ((row & 3) ^ ((row >> 2) & 3));
                    int gidx = (kk * 4 + lk) ^ sw;
                    b[n] = *(const short8*)(baseB + row * KS + gidx * 8);
                }
                #pragma unroll
                for (int m = 0; m < 4; ++m)
                    #pragma unroll
                    for (int n = 0; n < 4; ++n)
                        acc[m][n] = __builtin_amdgcn_mfma_f32_16x16x32_bf16(a[m], b[n], acc[m][n], 0, 0, 0);
            }
        }

        // epilogue: C/D layout col=lane&15, row=(lane>>4)*4+reg
        #pragma unroll
        for (int m = 0; m < 4; ++m) {
            #pragma unroll
            for (int n = 0; n < 4; ++n) {
                int col = col0 + wn * 64 + n * 16 + lr;
                float bv = (MODE == 1) ? bias[col] : 0.f;
                #pragma unroll
                for (int j = 0; j < 4; ++j) {
                    int rowg = row0 + wm * 64 + m * 16 + lk * 4 + j;
                    float v = acc[m][n][j];
                    if (MODE == 1) { v += bv; v = (v > 0.f) ? v : expm1f(v); }
                    C[(size_t)rowg * N + col] = f2bf(v);
                }
            }
        }
    } else if (DOTS == 2) {
        // layer-2 dots over the shared read-only input A (x16)
        int gw = ((int)blockIdx.x - ngemm) * 4 + (threadIdx.x >> 6);
        int lane = threadIdx.x & 63;
        if (gw >= NN) return;
        const ushortT* row = A + (size_t)gw * 1024 + lane * 16;
        short8 v0 = *(const short8*)row;
        short8 v1 = *(const short8*)(row + 8);
        float ps[8] = {0.f, 0.f, 0.f, 0.f, 0.f, 0.f, 0.f, 0.f};
        const float* wb = wsv + (size_t)lane * 16 * 8;
        #pragma unroll
        for (int c = 0; c < 8; ++c) {
            float xv = bf2f((ushortT)v0[c]);
            #pragma unroll
            for (int o = 0; o < 8; ++o) ps[o] += xv * wb[c * 8 + o];
        }
        #pragma unroll
        for (int c = 0; c < 8; ++c) {
            float xv = bf2f((ushortT)v1[c]);
            #pragma unroll
            for (int o = 0; o < 8; ++o) ps[o] += xv * wb[(8 + c) * 8 + o];
        }
        #pragma unroll
        for (int off = 1; off < 64; off <<= 1) {
            #pragma unroll
            for (int o = 0; o < 8; ++o) ps[o] += __shfl_xor(ps[o], off);
        }
        if (lane == 0) {
            #pragma unroll
            for (int h = 0; h < 4; ++h) { da_s[gw * 4 + h] = ps[h]; da_d[gw * 4 + h] = ps[4 + h]; }
        }
    } else if (DOTS == 3) {
        // layer-3 dots (heads=1) over the shared read-only input A (x16)
        int gw = ((int)blockIdx.x - ngemm) * 4 + (threadIdx.x >> 6);
        int lane = threadIdx.x & 63;
        if (gw >= NN) return;
        const ushortT* row = A + (size_t)gw * 1024 + lane * 16;
        short8 v0 = *(const short8*)row;
        short8 v1 = *(const short8*)(row + 8);
        float p0 = 0.f, p1 = 0.f;
        const int c0 = lane * 16;
        #pragma unroll
        for (int c = 0; c < 8; ++c) {
            float xv = bf2f((ushortT)v0[c]);
            float2 w2 = *(const float2*)(wsv + (size_t)(c0 + c) * 2);
            p0 += xv * w2.x; p1 += xv * w2.y;
        }
        #pragma unroll
        for (int c = 0; c < 8; ++c) {
            float xv = bf2f((ushortT)v1[c]);
            float2 w2 = *(const float2*)(wsv + (size_t)(c0 + 8 + c) * 2);
            p0 += xv * w2.x; p1 += xv * w2.y;
        }
        #pragma unroll
        for (int off = 1; off < 64; off <<= 1) {
            p0 += __shfl_xor(p0, off);
            p1 += __shfl_xor(p1, off);
        }
        if (lane == 0) { da_s[gw] = p0; da_d[gw] = p1; }
    }
}

// ---------------------------------------------------------------------------
// GAT aggregation heads=4 (C=1024): one WAVE per node, lane owns 16 ch.
// Measured floor ~60us (random edges; ~5.6 TB/s delivered, near copy ceiling).
// ---------------------------------------------------------------------------
__global__ __launch_bounds__(256) void gat_agg_h4(const ushortT* __restrict__ hfeat,
                                                  const float* __restrict__ a_s,
                                                  const float* __restrict__ a_d,
                                                  const int* __restrict__ rowp,
                                                  const int* __restrict__ colv,
                                                  const float* __restrict__ bias,
                                                  ushortT* __restrict__ out16) {
    const int wv = threadIdx.x >> 6, lane = threadIdx.x & 63;
    const int i = blockIdx.x * 4 + wv;
    if (i >= NN) return;
    const int c0 = lane * 16;
    const int hh = c0 >> 8;
    const int start = rowp[i], end = rowp[i + 1];

    __shared__ float wsh[4][64][4];
    __shared__ int   ssh[4][64];

    float acc[16];
    #pragma unroll
    for (int c = 0; c < 16; ++c) acc[c] = 0.f;
    float den4[4] = {0.f, 0.f, 0.f, 0.f};

    for (int cb = start; cb < end; cb += 64) {
        int clen = min(64, end - cb);
        if (lane < clen) {
            int s = colv[cb + lane];
            ssh[wv][lane] = s;
            float4 as4 = *(const float4*)(a_s + (size_t)s * 4);
            float4 ad4 = *(const float4*)(a_d + (size_t)i * 4);
            float l0 = as4.x + ad4.x; l0 = (l0 >= 0.f) ? l0 : 0.2f * l0;
            float l1 = as4.y + ad4.y; l1 = (l1 >= 0.f) ? l1 : 0.2f * l1;
            float l2 = as4.z + ad4.z; l2 = (l2 >= 0.f) ? l2 : 0.2f * l2;
            float l3 = as4.w + ad4.w; l3 = (l3 >= 0.f) ? l3 : 0.2f * l3;
            float w0 = expf(l0), w1 = expf(l1), w2 = expf(l2), w3 = expf(l3);
            *reinterpret_cast<float4*>(&wsh[wv][lane][0]) = make_float4(w0, w1, w2, w3);
            den4[0] += w0; den4[1] += w1; den4[2] += w2; den4[3] += w3;
        }
        __builtin_amdgcn_wave_barrier();
        int e = 0;
        for (; e + 4 <= clen; e += 4) {
            int sa = ssh[wv][e], sb = ssh[wv][e + 1], sc = ssh[wv][e + 2], sd = ssh[wv][e + 3];
            const ushortT* pa = hfeat + (size_t)sa * 1024 + c0;
            const ushortT* pb = hfeat + (size_t)sb * 1024 + c0;
            const ushortT* pc = hfeat + (size_t)sc * 1024 + c0;
            const ushortT* pd = hfeat + (size_t)sd * 1024 + c0;
            short8 va0 = *(const short8*)pa,       va1 = *(const short8*)(pa + 8);
            short8 vb0 = *(const short8*)pb,       vb1 = *(const short8*)(pb + 8);
            short8 vc0 = *(const short8*)pc,       vc1 = *(const short8*)(pc + 8);
            short8 vd0 = *(const short8*)pd,       vd1 = *(const short8*)(pd + 8);
            float wa = wsh[wv][e][hh],     wb = wsh[wv][e + 1][hh];
            float wc = wsh[wv][e + 2][hh], wd = wsh[wv][e + 3][hh];
            #pragma unroll
            for (int j = 0; j < 8; ++j) {
                acc[j]     += wa * bf2f((ushortT)va0[j]) + wb * bf2f((ushortT)vb0[j])
                            + wc * bf2f((ushortT)vc0[j]) + wd * bf2f((ushortT)vd0[j]);
                acc[8 + j] += wa * bf2f((ushortT)va1[j]) + wb * bf2f((ushortT)vb1[j])
                            + wc * bf2f((ushortT)vc1[j]) + wd * bf2f((ushortT)vd1[j]);
            }
        }
        for (; e < clen; ++e) {
            int s = ssh[wv][e];
            float wgt = wsh[wv][e][hh];
            const ushortT* p = hfeat + (size_t)s * 1024 + c0;
            short8 v0 = *(const short8*)p;
            short8 v1 = *(const short8*)(p + 8);
            #pragma unroll
            for (int j = 0; j < 8; ++j) {
                acc[j]     += wgt * bf2f((ushortT)v0[j]);
                acc[8 + j] += wgt * bf2f((ushortT)v1[j]);
            }
        }
        __builtin_amdgcn_wave_barrier();
    }

    #pragma unroll
    for (int off = 1; off < 64; off <<= 1) {
        den4[0] += __shfl_xor(den4[0], off);
        den4[1] += __shfl_xor(den4[1], off);
        den4[2] += __shfl_xor(den4[2], off);
        den4[3] += __shfl_xor(den4[3], off);
    }
    float den = (hh == 0) ? den4[0] : (hh == 1) ? den4[1] : (hh == 2) ? den4[2] : den4[3];
    float inv = 1.f / (den + 1e-16f);

    ushortT pk[16];
    #pragma unroll
    for (int c = 0; c < 16; ++c) {
        float v = acc[c] * inv + bias[c0 + c];
        v = (v > 0.f) ? v : expm1f(v);           // ELU
        pk[c] = f2bf(v);
    }
    *reinterpret_cast<short8*>(out16 + (size_t)i * 1024 + c0)     = *reinterpret_cast<short8*>(&pk[0]);
    *reinterpret_cast<short8*>(out16 + (size_t)i * 1024 + c0 + 8) = *reinterpret_cast<short8*>(&pk[8]);
}

// heads=1 (C=256): one wave per node, 4 channels/lane, fp32 out + bias + ELU.
__global__ __launch_bounds__(256) void gat_agg_h1(const ushortT* __restrict__ hfeat,
                                                  const float* __restrict__ a_s,
                                                  const float* __restrict__ a_d,
                                                  const int* __restrict__ rowp,
                                                  const int* __restrict__ colv,
                                                  const float* __restrict__ bias,
                                                  float* __restrict__ outf) {
    const int wv = threadIdx.x >> 6, lane = threadIdx.x & 63;
    const int i = blockIdx.x * 4 + wv;
    if (i >= NN) return;
    const int c0 = lane * 4;
    const int start = rowp[i], end = rowp[i + 1];
    const float adi = a_d[i];

    __shared__ float wsh[4][64];
    __shared__ int   ssh[4][64];

    float acc[4] = {0.f, 0.f, 0.f, 0.f};
    float den = 0.f;

    for (int cb = start; cb < end; cb += 64) {
        int clen = min(64, end - cb);
        if (lane < clen) {
            int s = colv[cb + lane];
            ssh[wv][lane] = s;
            float l = a_s[s] + adi;
            l = (l >= 0.f) ? l : 0.2f * l;
            float w0 = expf(l);
            wsh[wv][lane] = w0;
            den += w0;
        }
        __builtin_amdgcn_wave_barrier();
        int e = 0;
        for (; e + 4 <= clen; e += 4) {
            int sa = ssh[wv][e], sb = ssh[wv][e + 1], sc = ssh[wv][e + 2], sd = ssh[wv][e + 3];
            ushort4 va = *(const ushort4*)(hfeat + (size_t)sa * 256 + c0);
            ushort4 vb = *(const ushort4*)(hfeat + (size_t)sb * 256 + c0);
            ushort4 vc = *(const ushort4*)(hfeat + (size_t)sc * 256 + c0);
            ushort4 vd = *(const ushort4*)(hfeat + (size_t)sd * 256 + c0);
            float wa = wsh[wv][e], wb2 = wsh[wv][e + 1], wc2 = wsh[wv][e + 2], wd2 = wsh[wv][e + 3];
            acc[0] += wa * bf2f(va.x) + wb2 * bf2f(vb.x) + wc2 * bf2f(vc.x) + wd2 * bf2f(vd.x);
            acc[1] += wa * bf2f(va.y) + wb2 * bf2f(vb.y) + wc2 * bf2f(vc.y) + wd2 * bf2f(vd.y);
            acc[2] += wa * bf2f(va.z) + wb2 * bf2f(vb.z) + wc2 * bf2f(vc.z) + wd2 * bf2f(vd.z);
            acc[3] += wa * bf2f(va.w) + wb2 * bf2f(vb.w) + wc2 * bf2f(vc.w) + wd2 * bf2f(vd.w);
        }
        for (; e < clen; ++e) {
            int s = ssh[wv][e];
            float wgt = wsh[wv][e];
            ushort4 v = *(const ushort4*)(hfeat + (size_t)s * 256 + c0);
            acc[0] += wgt * bf2f(v.x); acc[1] += wgt * bf2f(v.y);
            acc[2] += wgt * bf2f(v.z); acc[3] += wgt * bf2f(v.w);
        }
        __builtin_amdgcn_wave_barrier();
    }

    #pragma unroll
    for (int off = 1; off < 64; off <<= 1) den += __shfl_xor(den, off);
    float inv = 1.f / (den + 1e-16f);

    float4 o4;
    float v0 = acc[0] * inv + bias[c0 + 0]; o4.x = (v0 > 0.f) ? v0 : expm1f(v0);
    float v1 = acc[1] * inv + bias[c0 + 1]; o4.y = (v1 > 0.f) ? v1 : expm1f(v1);
    float v2 = acc[2] * inv + bias[c0 + 2]; o4.z = (v2 > 0.f) ? v2 : expm1f(v2);
    float v3 = acc[3] * inv + bias[c0 + 3]; o4.w = (v3 > 0.f) ? v3 : expm1f(v3);
    *reinterpret_cast<float4*>(outf + (size_t)i * 256 + c0) = o4;
}

// ---------------------------------------------------------------------------
// global mean pool + MLP head
// ---------------------------------------------------------------------------
__global__ void pool_mlp(const float* __restrict__ x,
                         const int* __restrict__ batch,
                         const float* __restrict__ fc1_w,
                         const float* __restrict__ fc1_b,
                         const float* __restrict__ fc2_w,
                         const float* __restrict__ fc2_b,
                         float* __restrict__ out) {
    int g = blockIdx.x, tid = threadIdx.x;
    int lo = 0, hi = NN;
    while (lo < hi) { int mid = (lo + hi) >> 1; if (batch[mid] < g) lo = mid + 1; else hi = mid; }
    int s0 = lo;
    lo = 0; hi = NN;
    while (lo < hi) { int mid = (lo + hi) >> 1; if (batch[mid] < g + 1) lo = mid + 1; else hi = mid; }
    int s1 = lo;

    float acc = 0.f;
    for (int n = s0; n < s1; ++n) acc += x[(size_t)n * HID + tid];
    float cnt = (float)(s1 - s0);
    float feat = acc / fmaxf(cnt, 1.f);
    out[NG + g * HID + tid] = feat;

    __shared__ float fsh[HID];
    fsh[tid] = feat;
    __syncthreads();
    __shared__ float r2[128];
    if (tid < 128) {
        float a = fc1_b[tid];
        for (int c = 0; c < HID; ++c) a += fsh[c] * fc1_w[c * 128 + tid];
        a = fmaxf(a, 0.f);
        r2[tid] = a * fc2_w[tid];
    }
    __syncthreads();
    for (int s2 = 64; s2 > 0; s2 >>= 1) {
        if (tid < s2) r2[tid] += r2[tid + s2];
        __syncthreads();
    }
    if (tid == 0) out[g] = r2[0] + fc2_b[0];
}

// ---------------------------------------------------------------------------
extern "C" void kernel_launch(void* const* d_in, const int* in_sizes, int n_in,
                              void* d_out, int out_size, void* d_ws, size_t ws_size,
                              hipStream_t stream) {
    const float* atom  = (const float*)d_in[0];
    const int*   ei    = (const int*)  d_in[1];
    const int*   batch = (const int*)  d_in[2];
    const float* W1  = (const float*)d_in[3];
    const float* as1 = (const float*)d_in[4];
    const float* ad1 = (const float*)d_in[5];
    const float* b1  = (const float*)d_in[6];
    const float* W2  = (const float*)d_in[7];
    const float* as2 = (const float*)d_in[8];
    const float* ad2 = (const float*)d_in[9];
    const float* b2  = (const float*)d_in[10];
    const float* W3  = (const float*)d_in[11];
    const float* as3 = (const float*)d_in[12];
    const float* ad3 = (const float*)d_in[13];
    const float* b3  = (const float*)d_in[14];
    const float* fc1w = (const float*)d_in[15];
    const float* fc1b = (const float*)d_in[16];
    const float* fc2w = (const float*)d_in[17];
    const float* fc2b = (const float*)d_in[18];
    float* out = (float*)d_out;

    // workspace layout (16B-aligned sections; M-padded matrices)
    ushortT* h16  = (ushortT*)d_ws;                       // [MP,1024] bf16
    ushortT* x16  = h16 + (size_t)MP * 1024;              // [MP,1024] bf16
    ushortT* Ap   = x16 + (size_t)MP * 1024;              // [MP,128]  bf16
    ushortT* b1p  = Ap + (size_t)MP * 128;                // [1024,128] bf16
    ushortT* wt2  = b1p + 1024 * 128;                     // [1024,1024] bf16
    ushortT* wt3  = wt2 + 1024 * 1024;                    // [256,1024] bf16
    float*   x3   = (float*)(wt3 + 256 * 1024);           // [NN,256] f32
    float*   asL1 = x3 + (size_t)NN * 256;                // [NN,4]
    float*   adL1 = asL1 + (size_t)NN * 4;                // [NN,4]
    float*   asL2 = adL1 + (size_t)NN * 4;                // [NN,4]
    float*   adL2 = asL2 + (size_t)NN * 4;                // [NN,4]
    float*   asL3 = adL2 + (size_t)NN * 4;                // [NN]
    float*   adL3 = asL3 + NN;                            // [NN]
    float*   wsv1 = adL3 + NN;                            // [23,8]
    float*   wsv2 = wsv1 + 23 * 8;                        // [1024,8]
    float*   wsv3 = wsv2 + 1024 * 8;                      // [1024,2]
    int*   cnt    = (int*)(wsv3 + 1024 * 2);              // [NN]
    int*   rowp   = cnt + NN;                             // [NN+1]
    int*   cursor = rowp + NN + 1;                        // [NN]
    int*   col    = cursor + NN;                          // [ETOT]

    dim3 blk(256);
    const int gagg = (NN + 3) / 4;           // 2500
    const int gy   = MP / 128;               // 79

    // ---- setup (memset + 1 mega-launch incl. edge histogram) ----
    hipMemsetAsync(cnt, 0, NN * sizeof(int), stream);
    const int ecnt_blocks = (ETOT + 255) / 256;   // 665
    setup_kernel<<<4398 + ecnt_blocks, blk, 0, stream>>>(
        W1, as1, ad1, wsv1, W2, as2, ad2, wsv2,
        W3, as3, ad3, wsv3, wt2, wt3, b1p, ei, cnt);

    // ---- CSR scan + fill + layer-1 dots ----
    scan_kernel<<<1, blk, 0, stream>>>(cnt, rowp, cursor);
    fill_dots1_kernel<<<ecnt_blocks + (NN + 255) / 256, blk, 0, stream>>>(
        ei, cursor, col, atom, wsv1, asL1, adL1, ecnt_blocks);

    // ---- layer 1: aggregate raw atoms, block-diag GEMM (bias+ELU fused) ----
    agg_atom_kernel<<<gagg, blk, 0, stream>>>(atom, asL1, adL1, rowp, col, Ap);
    gemm_bf16<1, 32, 0><<<8 * gy, blk, 0, stream>>>(Ap, b1p, x16, b1, nullptr, nullptr, nullptr,
                                                    1024, 128, 8, 8 * gy);

    // ---- layer 2: GEMM(BK=64) + dots2 in one launch, then aggregate ----
    gemm_bf16<0, 64, 2><<<8 * gy + gagg, blk, 0, stream>>>(x16, wt2, h16, nullptr, wsv2,
                                                           asL2, adL2, 1024, 1024, 8, 8 * gy);
    gat_agg_h4<<<gagg, blk, 0, stream>>>(h16, asL2, adL2, rowp, col, b2, x16);

    // ---- layer 3: GEMM(BK=64) + dots3 in one launch, then aggregate ----
    gemm_bf16<0, 64, 3><<<2 * gy + gagg, blk, 0, stream>>>(x16, wt3, h16, nullptr, wsv3,
                                                           asL3, adL3, 256, 1024, 2, 2 * gy);
    gat_agg_h1<<<gagg, blk, 0, stream>>>(h16, asL3, adL3, rowp, col, b3, x3);

    // ---- pool + MLP head ----
    pool_mlp<<<NG, blk, 0, stream>>>(x3, batch, fc1w, fc1b, fc2w, fc2b, out);
}

// Round 12
// 290.609 us; speedup vs baseline: 1.0482x; 1.0104x over previous
//
#include <hip/hip_runtime.h>
#include <hip/hip_bf16.h>
#include <math.h>

typedef unsigned short ushortT;
typedef __attribute__((ext_vector_type(8))) short short8;
typedef __attribute__((ext_vector_type(4))) float f32x4;

// Problem constants (fixed by the reference)
constexpr int NN   = 10000;    // nodes
constexpr int MP   = 10112;    // NN padded to multiple of 128 (79*128)
constexpr int EE   = 160000;   // edges (before self-loops)
constexpr int ETOT = EE + NN;  // edges incl. self-loops
constexpr int NG   = 64;       // graphs
constexpr int HID  = 256;
constexpr int HEADS = 4;

__device__ __forceinline__ ushortT f2bf(float x) {
    __hip_bfloat16 h = __float2bfloat16(x);
    return *reinterpret_cast<ushortT*>(&h);
}
__device__ __forceinline__ float bf2f(ushortT x) {
    unsigned u = ((unsigned)x) << 16;
    return __uint_as_float(u);
}

// bijective XCD-chunk swizzle (m204 variant; works for any nwg)
__device__ __forceinline__ int xcd_swz(int flat, int nwg) {
    int q = nwg >> 3, r = nwg & 7;
    int xcd = flat & 7, j = flat >> 3;
    return (xcd < r ? xcd * (q + 1) : r * (q + 1) + (xcd - r) * q) + j;
}

// ---------------------------------------------------------------------------
// SETUP mega-kernel: W2/W3 transpose-convert, block-diag W1, attention
// projections (wsv1/2/3), and the CSR edge histogram (cnt pre-zeroed by
// memset).
// ---------------------------------------------------------------------------
__global__ __launch_bounds__(256) void setup_kernel(
        const float* __restrict__ W1, const float* __restrict__ as1,
        const float* __restrict__ ad1, float* __restrict__ wsv1,
        const float* __restrict__ W2, const float* __restrict__ as2,
        const float* __restrict__ ad2, float* __restrict__ wsv2,
        const float* __restrict__ W3, const float* __restrict__ as3,
        const float* __restrict__ ad3, float* __restrict__ wsv3,
        ushortT* __restrict__ wt2, ushortT* __restrict__ wt3,
        ushortT* __restrict__ b1p, const int* __restrict__ ei,
        int* __restrict__ cnt) {
    __shared__ float t[32][33];
    const int b = blockIdx.x, tid = threadIdx.x;
    if (b < 1280) {
        const float* W; ushortT* Wt; int N, n0, k0;
        if (b < 1024) { W = W2; Wt = wt2; N = 1024; n0 = (b & 31) * 32; k0 = (b >> 5) * 32; }
        else          { int b2 = b - 1024; W = W3; Wt = wt3; N = 256; n0 = (b2 & 7) * 32; k0 = (b2 >> 3) * 32; }
        const int K = 1024, Kp = 1024;
        int tx = tid & 31, ty = tid >> 5;
        for (int i = ty; i < 32; i += 8) {
            int k = k0 + i, n = n0 + tx;
            t[i][tx] = (k < K && n < N) ? W[(size_t)k * N + n] : 0.f;
        }
        __syncthreads();
        for (int i = ty; i < 32; i += 8) {
            int n = n0 + i, kp = k0 + tx;
            if (n < N && kp < Kp) Wt[(size_t)n * Kp + kp] = f2bf(t[tx][i]);
        }
    } else if (b < 1792) {
        int idx = (b - 1280) * 256 + tid;
        int n = idx >> 7, kp = idx & 127;
        int h = n >> 8, hk = kp >> 5, k = kp & 31;
        float v = (hk == h && k < 23) ? W1[(size_t)k * 1024 + n] : 0.f;
        b1p[idx] = f2bf(v);
    } else if (b < 4398) {
        int gw = (b - 1792) * 4 + (tid >> 6);
        int lane = tid & 63;
        const float *W, *atts, *attd; float* wsv; int heads, idx;
        if (gw < 184)            { W = W1; atts = as1; attd = ad1; wsv = wsv1; heads = 4; idx = gw; }
        else if (gw < 184 + 8192){ W = W2; atts = as2; attd = ad2; wsv = wsv2; heads = 4; idx = gw - 184; }
        else if (gw < 184 + 8192 + 2048) { W = W3; atts = as3; attd = ad3; wsv = wsv3; heads = 1; idx = gw - 184 - 8192; }
        else return;
        const int nout = 2 * heads;
        int k = idx / nout, o = idx - k * nout;
        int h = (o >= heads) ? (o - heads) : o;
        const float* att  = ((o >= heads) ? attd : atts) + h * HID;
        const float* wrow = W + (size_t)k * (heads * HID) + h * HID;
        float4 w4 = *(const float4*)(wrow + lane * 4);
        float4 a4 = *(const float4*)(att + lane * 4);
        float s = w4.x * a4.x + w4.y * a4.y + w4.z * a4.z + w4.w * a4.w;
        #pragma unroll
        for (int off = 1; off < 64; off <<= 1) s += __shfl_xor(s, off);
        if (lane == 0) wsv[(size_t)k * nout + o] = s;
    } else {
        int e = (b - 4398) * 256 + tid;
        if (e >= ETOT) return;
        int dst = (e < EE) ? ei[EE + e] : (e - EE);
        atomicAdd(&cnt[dst], 1);
    }
}

__global__ void scan_kernel(const int* __restrict__ cnt, int* __restrict__ row_ptr,
                            int* __restrict__ cursor) {
    __shared__ int part[256];
    int tid = threadIdx.x;
    const int chunk = (NN + 255) / 256;   // 40
    int s0 = tid * chunk;
    int s1 = min(NN, s0 + chunk);
    int sum = 0;
    for (int i = s0; i < s1; ++i) sum += cnt[i];
    part[tid] = sum;
    __syncthreads();
    for (int off = 1; off < 256; off <<= 1) {
        int v = (tid >= off) ? part[tid - off] : 0;
        __syncthreads();
        part[tid] += v;
        __syncthreads();
    }
    int run = (tid == 0) ? 0 : part[tid - 1];
    for (int i = s0; i < s1; ++i) {
        row_ptr[i] = run;
        cursor[i]  = run;
        run += cnt[i];
    }
    if (tid == 255) row_ptr[NN] = part[255];
}

// edge_fill + layer-1 dots (independent work) in one launch
__global__ void fill_dots1_kernel(const int* __restrict__ ei, int* __restrict__ cursor,
                                  int* __restrict__ col_src,
                                  const float* __restrict__ atom,
                                  const float* __restrict__ wsv1,
                                  float* __restrict__ a_s, float* __restrict__ a_d,
                                  int nfill) {
    int b = blockIdx.x;
    if (b < nfill) {
        int e = b * 256 + threadIdx.x;
        if (e >= ETOT) return;
        int src, dst;
        if (e < EE) { src = ei[e]; dst = ei[EE + e]; }
        else        { src = dst = e - EE; }
        int pos = atomicAdd(&cursor[dst], 1);
        col_src[pos] = src;
    } else {
        int n = (b - nfill) * 256 + threadIdx.x;
        if (n >= NN) return;
        float a[8] = {0.f, 0.f, 0.f, 0.f, 0.f, 0.f, 0.f, 0.f};
        #pragma unroll
        for (int k = 0; k < 23; ++k) {
            float x = atom[n * 23 + k];
            #pragma unroll
            for (int o = 0; o < 8; ++o) a[o] += x * wsv1[k * 8 + o];
        }
        #pragma unroll
        for (int h = 0; h < 4; ++h) { a_s[n * 4 + h] = a[h]; a_d[n * 4 + h] = a[4 + h]; }
    }
}

// ---------------------------------------------------------------------------
// layer-1 aggregate on RAW atom features
// ---------------------------------------------------------------------------
__global__ __launch_bounds__(256) void agg_atom_kernel(const float* __restrict__ atom,
                                                       const float* __restrict__ a_s,
                                                       const float* __restrict__ a_d,
                                                       const int* __restrict__ rowp,
                                                       const int* __restrict__ colv,
                                                       ushortT* __restrict__ Ap) {
    const int wv = threadIdx.x >> 6, lane = threadIdx.x & 63;
    const int i = blockIdx.x * 4 + wv;
    if (i >= NN) return;
    const int half = lane >> 5, c = lane & 31;
    const int start = rowp[i], end = rowp[i + 1];

    __shared__ float wsh[4][64][4];
    __shared__ int   ssh[4][64];

    float acc[4] = {0.f, 0.f, 0.f, 0.f};
    float den4[4] = {0.f, 0.f, 0.f, 0.f};
    for (int cb = start; cb < end; cb += 64) {
        int clen = min(64, end - cb);
        if (lane < clen) {
            int s = colv[cb + lane];
            ssh[wv][lane] = s;
            float4 as4 = *(const float4*)(a_s + (size_t)s * 4);
            float4 ad4 = *(const float4*)(a_d + (size_t)i * 4);
            float l0 = as4.x + ad4.x; l0 = (l0 >= 0.f) ? l0 : 0.2f * l0;
            float l1 = as4.y + ad4.y; l1 = (l1 >= 0.f) ? l1 : 0.2f * l1;
            float l2 = as4.z + ad4.z; l2 = (l2 >= 0.f) ? l2 : 0.2f * l2;
            float l3 = as4.w + ad4.w; l3 = (l3 >= 0.f) ? l3 : 0.2f * l3;
            float w0 = expf(l0), w1 = expf(l1), w2 = expf(l2), w3 = expf(l3);
            *reinterpret_cast<float4*>(&wsh[wv][lane][0]) = make_float4(w0, w1, w2, w3);
            den4[0] += w0; den4[1] += w1; den4[2] += w2; den4[3] += w3;
        }
        __builtin_amdgcn_wave_barrier();
        for (int e = half; e < clen; e += 2) {
            int s = ssh[wv][e];
            float x = (c < 23) ? atom[(size_t)s * 23 + c] : 0.f;
            acc[0] += wsh[wv][e][0] * x;
            acc[1] += wsh[wv][e][1] * x;
            acc[2] += wsh[wv][e][2] * x;
            acc[3] += wsh[wv][e][3] * x;
        }
        __builtin_amdgcn_wave_barrier();
    }
    #pragma unroll
    for (int h = 0; h < 4; ++h) acc[h] += __shfl_xor(acc[h], 32);
    #pragma unroll
    for (int off = 1; off < 64; off <<= 1) {
        den4[0] += __shfl_xor(den4[0], off);
        den4[1] += __shfl_xor(den4[1], off);
        den4[2] += __shfl_xor(den4[2], off);
        den4[3] += __shfl_xor(den4[3], off);
    }
    if (half == 0) {
        #pragma unroll
        for (int h = 0; h < 4; ++h) {
            float v = acc[h] / (den4[h] + 1e-16f);
            Ap[(size_t)i * 128 + h * 32 + c] = f2bf(v);
        }
    }
}

// ---------------------------------------------------------------------------
// bf16 MFMA GEMM, M = MP (padded). 512 threads = 8 waves (2M x 4N), per-wave
// 64x32 output (acc 4x2) — doubles waves/SIMD at the barrier vs 4-wave form
// to hide the vmcnt(0) drain latency. Templated K-step (32 or 64). Optional
// extra blocks run next-layer dot kernels over the shared read-only input A.
// MODE 0: plain bf16 store. MODE 1: +bias,ELU.
// ---------------------------------------------------------------------------
__device__ __forceinline__ void gload_lds16(const ushortT* gsrc, ushortT* ldst) {
    __builtin_amdgcn_global_load_lds(
        (const __attribute__((address_space(1))) unsigned int*)gsrc,
        (__attribute__((address_space(3))) unsigned int*)ldst, 16, 0, 0);
}

template<int MODE, int KS, int DOTS>
__global__ __launch_bounds__(512, 4) void gemm_bf16(const ushortT* __restrict__ A,
                                                    const ushortT* __restrict__ Bt,
                                                    ushortT* __restrict__ C,
                                                    const float* __restrict__ bias,
                                                    const float* __restrict__ wsv,
                                                    float* __restrict__ da_s,
                                                    float* __restrict__ da_d,
                                                    int N, int K, int nx, int ngemm) {
    __shared__ ushortT lds[2][2][128][KS];
    if ((int)blockIdx.x < ngemm) {
        const int tid  = threadIdx.x;
        const int lane = tid & 63, w = tid >> 6;
        const int wm = w >> 2, wn = w & 3;      // 2 x 4 waves, 64x32 out each
        const int swz  = xcd_swz(blockIdx.x, ngemm);
        const int bx = swz % nx, by = swz / nx;
        const int row0 = by * 128;
        const int col0 = bx * 128;
        const int nt = K / KS;
        constexpr int GPR = KS / 8;             // granules per row (4 or 8)
        constexpr int PT  = 128 * GPR / 512;    // granules per thread (1 or 2)

        auto stage = [&](int buf, int t) {
            int k0 = t * KS;
            #pragma unroll
            for (int i = 0; i < PT; ++i) {
                int g = i * 512 + tid;           // wave-contiguous LDS dest
                int row = g / GPR, gi = g % GPR;
                int sw = (KS == 64) ? (row & 7) : ((row & 3) ^ ((row >> 2) & 3));
                int koff = gi ^ sw;
                gload_lds16(A + (size_t)(row0 + row) * K + k0 + koff * 8,
                            &lds[buf][0][0][0] + g * 8);
                gload_lds16(Bt + (size_t)(col0 + row) * K + k0 + koff * 8,
                            &lds[buf][1][0][0] + g * 8);
            }
        };

        f32x4 acc[4][2] = {};
        const int lr = lane & 15, lk = lane >> 4;

        stage(0, 0);
        for (int t = 0; t < nt; ++t) {
            int buf = t & 1;
            __syncthreads();
            if (t + 1 < nt) stage(buf ^ 1, t + 1);
            const ushortT* baseA = &lds[buf][0][0][0];
            const ushortT* baseB = &lds[buf][1][0][0];
            #pragma unroll
            for (int kk = 0; kk < KS / 32; ++kk) {
                short8 a[4], b[2];
                #pragma unroll
                for (int m = 0; m < 4; ++m) {
                    int row = wm * 64 + m * 16 + lr;
                    int sw = (KS == 64) ? (row & 7) : ((row & 3) ^ ((row >> 2) & 3));
                    int gidx = (kk * 4 + lk) ^ sw;
                    a[m] = *(const short8*)(baseA + row * KS + gidx * 8);
                }
                #pragma unroll
                for (int n = 0; n < 2; ++n) {
                    int row = wn * 32 + n * 16 + lr;
                    int sw = (KS == 64) ? (row & 7) : ((row & 3) ^ ((row >> 2) & 3));
                    int gidx = (kk * 4 + lk) ^ sw;
                    b[n] = *(const short8*)(baseB + row * KS + gidx * 8);
                }
                #pragma unroll
                for (int m = 0; m < 4; ++m)
                    #pragma unroll
                    for (int n = 0; n < 2; ++n)
                        acc[m][n] = __builtin_amdgcn_mfma_f32_16x16x32_bf16(a[m], b[n], acc[m][n], 0, 0, 0);
            }
        }

        // epilogue: C/D layout col=lane&15, row=(lane>>4)*4+reg
        #pragma unroll
        for (int m = 0; m < 4; ++m) {
            #pragma unroll
            for (int n = 0; n < 2; ++n) {
                int col = col0 + wn * 32 + n * 16 + lr;
                float bv = (MODE == 1) ? bias[col] : 0.f;
                #pragma unroll
                for (int j = 0; j < 4; ++j) {
                    int rowg = row0 + wm * 64 + m * 16 + lk * 4 + j;
                    float v = acc[m][n][j];
                    if (MODE == 1) { v += bv; v = (v > 0.f) ? v : expm1f(v); }
                    C[(size_t)rowg * N + col] = f2bf(v);
                }
            }
        }
    } else if (DOTS == 2) {
        // layer-2 dots over the shared read-only input A (x16); 8 nodes/block
        int gw = ((int)blockIdx.x - ngemm) * 8 + (threadIdx.x >> 6);
        int lane = threadIdx.x & 63;
        if (gw >= NN) return;
        const ushortT* row = A + (size_t)gw * 1024 + lane * 16;
        short8 v0 = *(const short8*)row;
        short8 v1 = *(const short8*)(row + 8);
        float ps[8] = {0.f, 0.f, 0.f, 0.f, 0.f, 0.f, 0.f, 0.f};
        const float* wb = wsv + (size_t)lane * 16 * 8;
        #pragma unroll
        for (int c = 0; c < 8; ++c) {
            float xv = bf2f((ushortT)v0[c]);
            #pragma unroll
            for (int o = 0; o < 8; ++o) ps[o] += xv * wb[c * 8 + o];
        }
        #pragma unroll
        for (int c = 0; c < 8; ++c) {
            float xv = bf2f((ushortT)v1[c]);
            #pragma unroll
            for (int o = 0; o < 8; ++o) ps[o] += xv * wb[(8 + c) * 8 + o];
        }
        #pragma unroll
        for (int off = 1; off < 64; off <<= 1) {
            #pragma unroll
            for (int o = 0; o < 8; ++o) ps[o] += __shfl_xor(ps[o], off);
        }
        if (lane == 0) {
            #pragma unroll
            for (int h = 0; h < 4; ++h) { da_s[gw * 4 + h] = ps[h]; da_d[gw * 4 + h] = ps[4 + h]; }
        }
    } else if (DOTS == 3) {
        // layer-3 dots (heads=1) over the shared read-only input A (x16)
        int gw = ((int)blockIdx.x - ngemm) * 8 + (threadIdx.x >> 6);
        int lane = threadIdx.x & 63;
        if (gw >= NN) return;
        const ushortT* row = A + (size_t)gw * 1024 + lane * 16;
        short8 v0 = *(const short8*)row;
        short8 v1 = *(const short8*)(row + 8);
        float p0 = 0.f, p1 = 0.f;
        const int c0 = lane * 16;
        #pragma unroll
        for (int c = 0; c < 8; ++c) {
            float xv = bf2f((ushortT)v0[c]);
            float2 w2 = *(const float2*)(wsv + (size_t)(c0 + c) * 2);
            p0 += xv * w2.x; p1 += xv * w2.y;
        }
        #pragma unroll
        for (int c = 0; c < 8; ++c) {
            float xv = bf2f((ushortT)v1[c]);
            float2 w2 = *(const float2*)(wsv + (size_t)(c0 + 8 + c) * 2);
            p0 += xv * w2.x; p1 += xv * w2.y;
        }
        #pragma unroll
        for (int off = 1; off < 64; off <<= 1) {
            p0 += __shfl_xor(p0, off);
            p1 += __shfl_xor(p1, off);
        }
        if (lane == 0) { da_s[gw] = p0; da_d[gw] = p1; }
    }
}

// ---------------------------------------------------------------------------
// GAT aggregation heads=4 (C=1024): one WAVE per node, lane owns 16 ch.
// Measured floor ~60us (random edges; ~5.6 TB/s delivered, near copy ceiling).
// ---------------------------------------------------------------------------
__global__ __launch_bounds__(256) void gat_agg_h4(const ushortT* __restrict__ hfeat,
                                                  const float* __restrict__ a_s,
                                                  const float* __restrict__ a_d,
                                                  const int* __restrict__ rowp,
                                                  const int* __restrict__ colv,
                                                  const float* __restrict__ bias,
                                                  ushortT* __restrict__ out16) {
    const int wv = threadIdx.x >> 6, lane = threadIdx.x & 63;
    const int i = blockIdx.x * 4 + wv;
    if (i >= NN) return;
    const int c0 = lane * 16;
    const int hh = c0 >> 8;
    const int start = rowp[i], end = rowp[i + 1];

    __shared__ float wsh[4][64][4];
    __shared__ int   ssh[4][64];

    float acc[16];
    #pragma unroll
    for (int c = 0; c < 16; ++c) acc[c] = 0.f;
    float den4[4] = {0.f, 0.f, 0.f, 0.f};

    for (int cb = start; cb < end; cb += 64) {
        int clen = min(64, end - cb);
        if (lane < clen) {
            int s = colv[cb + lane];
            ssh[wv][lane] = s;
            float4 as4 = *(const float4*)(a_s + (size_t)s * 4);
            float4 ad4 = *(const float4*)(a_d + (size_t)i * 4);
            float l0 = as4.x + ad4.x; l0 = (l0 >= 0.f) ? l0 : 0.2f * l0;
            float l1 = as4.y + ad4.y; l1 = (l1 >= 0.f) ? l1 : 0.2f * l1;
            float l2 = as4.z + ad4.z; l2 = (l2 >= 0.f) ? l2 : 0.2f * l2;
            float l3 = as4.w + ad4.w; l3 = (l3 >= 0.f) ? l3 : 0.2f * l3;
            float w0 = expf(l0), w1 = expf(l1), w2 = expf(l2), w3 = expf(l3);
            *reinterpret_cast<float4*>(&wsh[wv][lane][0]) = make_float4(w0, w1, w2, w3);
            den4[0] += w0; den4[1] += w1; den4[2] += w2; den4[3] += w3;
        }
        __builtin_amdgcn_wave_barrier();
        int e = 0;
        for (; e + 4 <= clen; e += 4) {
            int sa = ssh[wv][e], sb = ssh[wv][e + 1], sc = ssh[wv][e + 2], sd = ssh[wv][e + 3];
            const ushortT* pa = hfeat + (size_t)sa * 1024 + c0;
            const ushortT* pb = hfeat + (size_t)sb * 1024 + c0;
            const ushortT* pc = hfeat + (size_t)sc * 1024 + c0;
            const ushortT* pd = hfeat + (size_t)sd * 1024 + c0;
            short8 va0 = *(const short8*)pa,       va1 = *(const short8*)(pa + 8);
            short8 vb0 = *(const short8*)pb,       vb1 = *(const short8*)(pb + 8);
            short8 vc0 = *(const short8*)pc,       vc1 = *(const short8*)(pc + 8);
            short8 vd0 = *(const short8*)pd,       vd1 = *(const short8*)(pd + 8);
            float wa = wsh[wv][e][hh],     wb = wsh[wv][e + 1][hh];
            float wc = wsh[wv][e + 2][hh], wd = wsh[wv][e + 3][hh];
            #pragma unroll
            for (int j = 0; j < 8; ++j) {
                acc[j]     += wa * bf2f((ushortT)va0[j]) + wb * bf2f((ushortT)vb0[j])
                            + wc * bf2f((ushortT)vc0[j]) + wd * bf2f((ushortT)vd0[j]);
                acc[8 + j] += wa * bf2f((ushortT)va1[j]) + wb * bf2f((ushortT)vb1[j])
                            + wc * bf2f((ushortT)vc1[j]) + wd * bf2f((ushortT)vd1[j]);
            }
        }
        for (; e < clen; ++e) {
            int s = ssh[wv][e];
            float wgt = wsh[wv][e][hh];
            const ushortT* p = hfeat + (size_t)s * 1024 + c0;
            short8 v0 = *(const short8*)p;
            short8 v1 = *(const short8*)(p + 8);
            #pragma unroll
            for (int j = 0; j < 8; ++j) {
                acc[j]     += wgt * bf2f((ushortT)v0[j]);
                acc[8 + j] += wgt * bf2f((ushortT)v1[j]);
            }
        }
        __builtin_amdgcn_wave_barrier();
    }

    #pragma unroll
    for (int off = 1; off < 64; off <<= 1) {
        den4[0] += __shfl_xor(den4[0], off);
        den4[1] += __shfl_xor(den4[1], off);
        den4[2] += __shfl_xor(den4[2], off);
        den4[3] += __shfl_xor(den4[3], off);
    }
    float den = (hh == 0) ? den4[0] : (hh == 1) ? den4[1] : (hh == 2) ? den4[2] : den4[3];
    float inv = 1.f / (den + 1e-16f);

    ushortT pk[16];
    #pragma unroll
    for (int c = 0; c < 16; ++c) {
        float v = acc[c] * inv + bias[c0 + c];
        v = (v > 0.f) ? v : expm1f(v);           // ELU
        pk[c] = f2bf(v);
    }
    *reinterpret_cast<short8*>(out16 + (size_t)i * 1024 + c0)     = *reinterpret_cast<short8*>(&pk[0]);
    *reinterpret_cast<short8*>(out16 + (size_t)i * 1024 + c0 + 8) = *reinterpret_cast<short8*>(&pk[8]);
}

// heads=1 (C=256): one wave per node, 4 channels/lane, fp32 out + bias + ELU.
__global__ __launch_bounds__(256) void gat_agg_h1(const ushortT* __restrict__ hfeat,
                                                  const float* __restrict__ a_s,
                                                  const float* __restrict__ a_d,
                                                  const int* __restrict__ rowp,
                                                  const int* __restrict__ colv,
                                                  const float* __restrict__ bias,
                                                  float* __restrict__ outf) {
    const int wv = threadIdx.x >> 6, lane = threadIdx.x & 63;
    const int i = blockIdx.x * 4 + wv;
    if (i >= NN) return;
    const int c0 = lane * 4;
    const int start = rowp[i], end = rowp[i + 1];
    const float adi = a_d[i];

    __shared__ float wsh[4][64];
    __shared__ int   ssh[4][64];

    float acc[4] = {0.f, 0.f, 0.f, 0.f};
    float den = 0.f;

    for (int cb = start; cb < end; cb += 64) {
        int clen = min(64, end - cb);
        if (lane < clen) {
            int s = colv[cb + lane];
            ssh[wv][lane] = s;
            float l = a_s[s] + adi;
            l = (l >= 0.f) ? l : 0.2f * l;
            float w0 = expf(l);
            wsh[wv][lane] = w0;
            den += w0;
        }
        __builtin_amdgcn_wave_barrier();
        int e = 0;
        for (; e + 4 <= clen; e += 4) {
            int sa = ssh[wv][e], sb = ssh[wv][e + 1], sc = ssh[wv][e + 2], sd = ssh[wv][e + 3];
            ushort4 va = *(const ushort4*)(hfeat + (size_t)sa * 256 + c0);
            ushort4 vb = *(const ushort4*)(hfeat + (size_t)sb * 256 + c0);
            ushort4 vc = *(const ushort4*)(hfeat + (size_t)sc * 256 + c0);
            ushort4 vd = *(const ushort4*)(hfeat + (size_t)sd * 256 + c0);
            float wa = wsh[wv][e], wb2 = wsh[wv][e + 1], wc2 = wsh[wv][e + 2], wd2 = wsh[wv][e + 3];
            acc[0] += wa * bf2f(va.x) + wb2 * bf2f(vb.x) + wc2 * bf2f(vc.x) + wd2 * bf2f(vd.x);
            acc[1] += wa * bf2f(va.y) + wb2 * bf2f(vb.y) + wc2 * bf2f(vc.y) + wd2 * bf2f(vd.y);
            acc[2] += wa * bf2f(va.z) + wb2 * bf2f(vb.z) + wc2 * bf2f(vc.z) + wd2 * bf2f(vd.z);
            acc[3] += wa * bf2f(va.w) + wb2 * bf2f(vb.w) + wc2 * bf2f(vc.w) + wd2 * bf2f(vd.w);
        }
        for (; e < clen; ++e) {
            int s = ssh[wv][e];
            float wgt = wsh[wv][e];
            ushort4 v = *(const ushort4*)(hfeat + (size_t)s * 256 + c0);
            acc[0] += wgt * bf2f(v.x); acc[1] += wgt * bf2f(v.y);
            acc[2] += wgt * bf2f(v.z); acc[3] += wgt * bf2f(v.w);
        }
        __builtin_amdgcn_wave_barrier();
    }

    #pragma unroll
    for (int off = 1; off < 64; off <<= 1) den += __shfl_xor(den, off);
    float inv = 1.f / (den + 1e-16f);

    float4 o4;
    float v0 = acc[0] * inv + bias[c0 + 0]; o4.x = (v0 > 0.f) ? v0 : expm1f(v0);
    float v1 = acc[1] * inv + bias[c0 + 1]; o4.y = (v1 > 0.f) ? v1 : expm1f(v1);
    float v2 = acc[2] * inv + bias[c0 + 2]; o4.z = (v2 > 0.f) ? v2 : expm1f(v2);
    float v3 = acc[3] * inv + bias[c0 + 3]; o4.w = (v3 > 0.f) ? v3 : expm1f(v3);
    *reinterpret_cast<float4*>(outf + (size_t)i * 256 + c0) = o4;
}

// ---------------------------------------------------------------------------
// global mean pool + MLP head
// ---------------------------------------------------------------------------
__global__ void pool_mlp(const float* __restrict__ x,
                         const int* __restrict__ batch,
                         const float* __restrict__ fc1_w,
                         const float* __restrict__ fc1_b,
                         const float* __restrict__ fc2_w,
                         const float* __restrict__ fc2_b,
                         float* __restrict__ out) {
    int g = blockIdx.x, tid = threadIdx.x;
    int lo = 0, hi = NN;
    while (lo < hi) { int mid = (lo + hi) >> 1; if (batch[mid] < g) lo = mid + 1; else hi = mid; }
    int s0 = lo;
    lo = 0; hi = NN;
    while (lo < hi) { int mid = (lo + hi) >> 1; if (batch[mid] < g + 1) lo = mid + 1; else hi = mid; }
    int s1 = lo;

    float acc = 0.f;
    for (int n = s0; n < s1; ++n) acc += x[(size_t)n * HID + tid];
    float cnt = (float)(s1 - s0);
    float feat = acc / fmaxf(cnt, 1.f);
    out[NG + g * HID + tid] = feat;

    __shared__ float fsh[HID];
    fsh[tid] = feat;
    __syncthreads();
    __shared__ float r2[128];
    if (tid < 128) {
        float a = fc1_b[tid];
        for (int c = 0; c < HID; ++c) a += fsh[c] * fc1_w[c * 128 + tid];
        a = fmaxf(a, 0.f);
        r2[tid] = a * fc2_w[tid];
    }
    __syncthreads();
    for (int s2 = 64; s2 > 0; s2 >>= 1) {
        if (tid < s2) r2[tid] += r2[tid + s2];
        __syncthreads();
    }
    if (tid == 0) out[g] = r2[0] + fc2_b[0];
}

// ---------------------------------------------------------------------------
extern "C" void kernel_launch(void* const* d_in, const int* in_sizes, int n_in,
                              void* d_out, int out_size, void* d_ws, size_t ws_size,
                              hipStream_t stream) {
    const float* atom  = (const float*)d_in[0];
    const int*   ei    = (const int*)  d_in[1];
    const int*   batch = (const int*)  d_in[2];
    const float* W1  = (const float*)d_in[3];
    const float* as1 = (const float*)d_in[4];
    const float* ad1 = (const float*)d_in[5];
    const float* b1  = (const float*)d_in[6];
    const float* W2  = (const float*)d_in[7];
    const float* as2 = (const float*)d_in[8];
    const float* ad2 = (const float*)d_in[9];
    const float* b2  = (const float*)d_in[10];
    const float* W3  = (const float*)d_in[11];
    const float* as3 = (const float*)d_in[12];
    const float* ad3 = (const float*)d_in[13];
    const float* b3  = (const float*)d_in[14];
    const float* fc1w = (const float*)d_in[15];
    const float* fc1b = (const float*)d_in[16];
    const float* fc2w = (const float*)d_in[17];
    const float* fc2b = (const float*)d_in[18];
    float* out = (float*)d_out;

    // workspace layout (16B-aligned sections; M-padded matrices)
    ushortT* h16  = (ushortT*)d_ws;                       // [MP,1024] bf16
    ushortT* x16  = h16 + (size_t)MP * 1024;              // [MP,1024] bf16
    ushortT* Ap   = x16 + (size_t)MP * 1024;              // [MP,128]  bf16
    ushortT* b1p  = Ap + (size_t)MP * 128;                // [1024,128] bf16
    ushortT* wt2  = b1p + 1024 * 128;                     // [1024,1024] bf16
    ushortT* wt3  = wt2 + 1024 * 1024;                    // [256,1024] bf16
    float*   x3   = (float*)(wt3 + 256 * 1024);           // [NN,256] f32
    float*   asL1 = x3 + (size_t)NN * 256;                // [NN,4]
    float*   adL1 = asL1 + (size_t)NN * 4;                // [NN,4]
    float*   asL2 = adL1 + (size_t)NN * 4;                // [NN,4]
    float*   adL2 = asL2 + (size_t)NN * 4;                // [NN,4]
    float*   asL3 = adL2 + (size_t)NN * 4;                // [NN]
    float*   adL3 = asL3 + NN;                            // [NN]
    float*   wsv1 = adL3 + NN;                            // [23,8]
    float*   wsv2 = wsv1 + 23 * 8;                        // [1024,8]
    float*   wsv3 = wsv2 + 1024 * 8;                      // [1024,2]
    int*   cnt    = (int*)(wsv3 + 1024 * 2);              // [NN]
    int*   rowp   = cnt + NN;                             // [NN+1]
    int*   cursor = rowp + NN + 1;                        // [NN]
    int*   col    = cursor + NN;                          // [ETOT]

    dim3 blk(256), blk512(512);
    const int gagg  = (NN + 3) / 4;          // 2500
    const int gy    = MP / 128;              // 79
    const int nd8   = (NN + 7) / 8;          // 1250 (dots blocks, 8 waves)

    // ---- setup (memset + 1 mega-launch incl. edge histogram) ----
    hipMemsetAsync(cnt, 0, NN * sizeof(int), stream);
    const int ecnt_blocks = (ETOT + 255) / 256;   // 665
    setup_kernel<<<4398 + ecnt_blocks, blk, 0, stream>>>(
        W1, as1, ad1, wsv1, W2, as2, ad2, wsv2,
        W3, as3, ad3, wsv3, wt2, wt3, b1p, ei, cnt);

    // ---- CSR scan + fill + layer-1 dots ----
    scan_kernel<<<1, blk, 0, stream>>>(cnt, rowp, cursor);
    fill_dots1_kernel<<<ecnt_blocks + (NN + 255) / 256, blk, 0, stream>>>(
        ei, cursor, col, atom, wsv1, asL1, adL1, ecnt_blocks);

    // ---- layer 1: aggregate raw atoms, block-diag GEMM (bias+ELU fused) ----
    agg_atom_kernel<<<gagg, blk, 0, stream>>>(atom, asL1, adL1, rowp, col, Ap);
    gemm_bf16<1, 32, 0><<<8 * gy, blk512, 0, stream>>>(Ap, b1p, x16, b1, nullptr, nullptr, nullptr,
                                                       1024, 128, 8, 8 * gy);

    // ---- layer 2: GEMM(BK=64, 8-wave) + dots2 in one launch, then aggregate ----
    gemm_bf16<0, 64, 2><<<8 * gy + nd8, blk512, 0, stream>>>(x16, wt2, h16, nullptr, wsv2,
                                                             asL2, adL2, 1024, 1024, 8, 8 * gy);
    gat_agg_h4<<<gagg, blk, 0, stream>>>(h16, asL2, adL2, rowp, col, b2, x16);

    // ---- layer 3: GEMM(BK=64, 8-wave) + dots3 in one launch, then aggregate ----
    gemm_bf16<0, 64, 3><<<2 * gy + nd8, blk512, 0, stream>>>(x16, wt3, h16, nullptr, wsv3,
                                                             asL3, adL3, 256, 1024, 2, 2 * gy);
    gat_agg_h1<<<gagg, blk, 0, stream>>>(h16, asL3, adL3, rowp, col, b3, x3);

    // ---- pool + MLP head ----
    pool_mlp<<<NG, blk, 0, stream>>>(x3, batch, fc1w, fc1b, fc2w, fc2b, out);
}